// Round 1
// baseline (453.850 us; speedup 1.0000x reference)
//
#include <hip/hip_runtime.h>
#include <stdint.h>

// ---- types ----
typedef __attribute__((ext_vector_type(8))) short bf16x8;     // 8 x bf16 (as shorts) = 4 VGPR
typedef __attribute__((ext_vector_type(4))) float f32x4;
typedef __attribute__((ext_vector_type(4))) unsigned short us4;
typedef __attribute__((ext_vector_type(8))) unsigned short us8;

// fp32 -> bf16 round-to-nearest-even (self-contained)
static __device__ __forceinline__ unsigned short f2bf(float f) {
  union { float f; unsigned u; } c; c.f = f;
  unsigned r = c.u + 0x7fffu + ((c.u >> 16) & 1u);
  return (unsigned short)(r >> 16);
}

// Problem constants: x (r=64, i=256, n=2, E=768), h=12, d=64
// tokens T = 32768 in (r,i,n) order; scores K-dim = r*d = 4096; hn = 24 slabs.
#define LDP 80   // padded LDS row length in ushorts (160B rows: 16B-aligned, uniform bank spread)

// ======================================================================
// Shared GEMM core: C(128x128) += A(128xK) * B^T, B stored [col][k].
// 256 threads = 4 waves in 2x2, each wave 64x64 = 4x4 MFMA 16x16x32 frags.
// A and B are both k-contiguous rows -> identical 16B fragment loads.
// ======================================================================
__device__ __forceinline__ void gemm_core(
    const unsigned short* __restrict__ Ag, int lda,
    const unsigned short* __restrict__ Bg, int ldb,
    int K, unsigned short* As, unsigned short* Bs, f32x4 acc[4][4])
{
  const int tid  = threadIdx.x;
  const int lane = tid & 63;
  const int wid  = tid >> 6;
  const int wr = wid >> 1, wc = wid & 1;
  const int lr = lane & 15, kg = lane >> 4;

  for (int kt = 0; kt < K; kt += 64) {
    us8 av[4], bv[4];
#pragma unroll
    for (int c = 0; c < 4; ++c) {      // 1024 16B-chunks per tile, 4 per thread
      int idx = c * 256 + tid, row = idx >> 3, ch = idx & 7;
      av[c] = *reinterpret_cast<const us8*>(Ag + row * lda + kt + ch * 8);
      bv[c] = *reinterpret_cast<const us8*>(Bg + row * ldb + kt + ch * 8);
    }
    __syncthreads();                   // prior compute done before overwrite
#pragma unroll
    for (int c = 0; c < 4; ++c) {
      int idx = c * 256 + tid, row = idx >> 3, ch = idx & 7;
      *reinterpret_cast<us8*>(As + row * LDP + ch * 8) = av[c];
      *reinterpret_cast<us8*>(Bs + row * LDP + ch * 8) = bv[c];
    }
    __syncthreads();
#pragma unroll
    for (int ks = 0; ks < 2; ++ks) {   // two k=32 sub-steps per BK=64
      bf16x8 af[4], bfr[4];
#pragma unroll
      for (int mi = 0; mi < 4; ++mi)
        af[mi] = *reinterpret_cast<const bf16x8*>(As + (wr*64 + mi*16 + lr) * LDP + ks*32 + kg*8);
#pragma unroll
      for (int ni = 0; ni < 4; ++ni)
        bfr[ni] = *reinterpret_cast<const bf16x8*>(Bs + (wc*64 + ni*16 + lr) * LDP + ks*32 + kg*8);
#pragma unroll
      for (int mi = 0; mi < 4; ++mi)
#pragma unroll
        for (int ni = 0; ni < 4; ++ni)
          acc[mi][ni] = __builtin_amdgcn_mfma_f32_16x16x32_bf16(af[mi], bfr[ni], acc[mi][ni], 0, 0, 0);
    }
  }
}

#define ACC_ZERO(acc) do { \
  f32x4 z = {0.f, 0.f, 0.f, 0.f}; \
  for (int a_ = 0; a_ < 4; ++a_) for (int b_ = 0; b_ < 4; ++b_) acc[a_][b_] = z; } while (0)

#define EPI_VARS \
  int tid = threadIdx.x, lane = tid & 63, wid = tid >> 6; \
  int wr = wid >> 1, wc = wid & 1, lr = lane & 15, kg = lane >> 4; (void)wr; (void)wc;

// ======================================================================
// Kernels
// ======================================================================

// x fp32 -> bf16, 4 elems/thread. grid 24576x256 covers 25165824 exactly.
__global__ __launch_bounds__(256) void k_cvt_x(const float* __restrict__ x,
                                               unsigned short* __restrict__ xb) {
  int i = blockIdx.x * 256 + threadIdx.x;
  f32x4 f = reinterpret_cast<const f32x4*>(x)[i];
  us4 o = { f2bf(f[0]), f2bf(f[1]), f2bf(f[2]), f2bf(f[3]) };
  reinterpret_cast<us4*>(xb)[i] = o;
}

// Build transposed bf16 weights wT[col][k] (q-part pre-scaled by 1/64),
// woT[col][k], and fused bias bqkv (q-part scaled). grid 9225x256 = 2361600 exactly.
__global__ __launch_bounds__(256) void k_cvt_w(
    const float* __restrict__ Wq, const float* __restrict__ Wk, const float* __restrict__ Wv,
    const float* __restrict__ Wo, const float* __restrict__ bq, const float* __restrict__ bk,
    const float* __restrict__ bv, unsigned short* __restrict__ wT,
    unsigned short* __restrict__ woT, float* __restrict__ bqkv)
{
  const float qs = 1.0f / 64.0f;  // d^-0.5 / sqrt(r) = (1/8)/8
  int o = blockIdx.x * 256 + threadIdx.x;
  if (o < 2304 * 768) {
    int col = o / 768, k = o % 768;
    float v;
    if (col < 768)       v = Wq[k * 768 + col] * qs;
    else if (col < 1536) v = Wk[k * 768 + col - 768];
    else                 v = Wv[k * 768 + col - 1536];
    wT[o] = f2bf(v);
  } else if (o < 2304 * 768 + 768 * 768) {
    int o2 = o - 2304 * 768;
    int col = o2 / 768, k = o2 % 768;
    woT[o2] = f2bf(Wo[k * 768 + col]);
  } else {
    int o3 = o - (2304 * 768 + 768 * 768);
    float v = (o3 < 768) ? bq[o3] * qs : (o3 < 1536 ? bk[o3 - 768] : bv[o3 - 1536]);
    bqkv[o3] = v;
  }
}

// QKV projection: qkvb[t][0..2303] = bf16(x @ [Wq|Wk|Wv] + b). grid 4608 (bn-fast for L2).
__global__ __launch_bounds__(256) void k_gemm_qkv(
    const unsigned short* __restrict__ xb, const unsigned short* __restrict__ wT,
    const float* __restrict__ bqkv, unsigned short* __restrict__ qkvb)
{
  __shared__ unsigned short As[128 * LDP], Bs[128 * LDP];
  int bx = blockIdx.x, bn = bx % 18, bm = bx / 18;
  f32x4 acc[4][4]; ACC_ZERO(acc);
  gemm_core(xb + (size_t)bm * 128 * 768, 768, wT + (size_t)bn * 128 * 768, 768, 768, As, Bs, acc);
  EPI_VARS;
#pragma unroll
  for (int mi = 0; mi < 4; ++mi)
#pragma unroll
    for (int ni = 0; ni < 4; ++ni) {
      int col = bn * 128 + wc * 64 + ni * 16 + lr;
      float bias = bqkv[col];
#pragma unroll
      for (int e = 0; e < 4; ++e) {
        int row = bm * 128 + wr * 64 + mi * 16 + kg * 4 + e;   // token
        qkvb[(size_t)row * 2304 + col] = f2bf(acc[mi][ni][e] + bias);
      }
    }
}

// Repack q/k -> [h][n][i][rr*64+dd] (k-contiguous for MFMA frags). Pure copy, both sides
// dd-contiguous. grid 24576x256, 4 elems/thread.
__global__ __launch_bounds__(256) void k_repack_qk(
    const unsigned short* __restrict__ qkvb, unsigned short* __restrict__ dst, int srcoff)
{
  int o4 = blockIdx.x * 256 + threadIdx.x;
  int o = o4 * 4;
  int dd = o & 63, rr = (o >> 6) & 63, ii = (o >> 12) & 255, nn = (o >> 20) & 1, h = o >> 21;
  int src = ((rr * 256 + ii) * 2 + nn) * 2304 + srcoff + h * 64 + dd;
  reinterpret_cast<us4*>(dst)[o4] = *reinterpret_cast<const us4*>(qkvb + src);
}

// Repack v -> V[h][n][rr*64+dd][j] (j-contiguous) via LDS 64x64 transpose tile.
// grid = 24*64*4 = 6144 blocks.
__global__ __launch_bounds__(256) void k_repack_v(
    const unsigned short* __restrict__ qkvb, unsigned short* __restrict__ V)
{
  __shared__ unsigned short lds[64 * LDP];
  int bx = blockIdx.x;
  int jt = bx & 3, rr = (bx >> 2) & 63, hn = bx >> 8;
  int h = hn >> 1, nn = hn & 1;
  int t = threadIdx.x;
  int j = t >> 3, ch = t & 7;
#pragma unroll
  for (int p = 0; p < 2; ++p) {
    int jj = p * 32 + j;
    us8 v = *reinterpret_cast<const us8*>(
        qkvb + ((size_t)((rr * 256 + jt * 64 + jj) * 2 + nn)) * 2304 + 1536 + h * 64 + ch * 8);
#pragma unroll
    for (int e = 0; e < 8; ++e) lds[(ch * 8 + e) * LDP + jj] = v[e];
  }
  __syncthreads();
  int dd = t >> 2, cj = t & 3;
  size_t ob = ((size_t)(hn * 64 + rr) * 64) * 256;
#pragma unroll
  for (int p = 0; p < 2; ++p) {
    int c2 = cj + p * 4;
    us8 v = *reinterpret_cast<const us8*>(lds + dd * LDP + c2 * 8);
    *reinterpret_cast<us8*>(V + ob + (size_t)dd * 256 + jt * 64 + c2 * 8) = v;
  }
}

// Scores: per (h,n): S[i][j] = sum_{r,d} Q K (K-dim 4096). grid 24*4 = 96.
__global__ __launch_bounds__(256) void k_gemm_scores(
    const unsigned short* __restrict__ Qb, const unsigned short* __restrict__ Kb,
    float* __restrict__ S)
{
  __shared__ unsigned short As[128 * LDP], Bs[128 * LDP];
  int bx = blockIdx.x;
  int hn = bx >> 2, tt = bx & 3, bm = tt >> 1, bn = tt & 1;
  f32x4 acc[4][4]; ACC_ZERO(acc);
  const unsigned short* Ag = Qb + (size_t)hn * 256 * 4096 + (size_t)bm * 128 * 4096;
  const unsigned short* Bg = Kb + (size_t)hn * 256 * 4096 + (size_t)bn * 128 * 4096;
  gemm_core(Ag, 4096, Bg, 4096, 4096, As, Bs, acc);
  EPI_VARS;
  float* Ss = S + (size_t)hn * 65536;
#pragma unroll
  for (int mi = 0; mi < 4; ++mi)
#pragma unroll
    for (int ni = 0; ni < 4; ++ni)
#pragma unroll
      for (int e = 0; e < 4; ++e) {
        int row = bm * 128 + wr * 64 + mi * 16 + kg * 4 + e;
        int col = bn * 128 + wc * 64 + ni * 16 + lr;
        Ss[(size_t)row * 256 + col] = acc[mi][ni][e];
      }
}

// Row softmax over j=256: one block per (hn,i) row. grid 6144.
__global__ __launch_bounds__(256) void k_softmax(const float* __restrict__ S,
                                                 unsigned short* __restrict__ P)
{
  __shared__ float red[8];
  size_t row = blockIdx.x;
  int t = threadIdx.x, wid = t >> 6, lane = t & 63;
  float v = S[row * 256 + t];
  float m = v;
#pragma unroll
  for (int o = 32; o; o >>= 1) m = fmaxf(m, __shfl_xor(m, o));
  if (lane == 0) red[wid] = m;
  __syncthreads();
  m = fmaxf(fmaxf(red[0], red[1]), fmaxf(red[2], red[3]));
  float e = __expf(v - m);
  float sm = e;
#pragma unroll
  for (int o = 32; o; o >>= 1) sm += __shfl_xor(sm, o);
  if (lane == 0) red[4 + wid] = sm;
  __syncthreads();
  sm = red[4] + red[5] + red[6] + red[7];
  P[row * 256 + t] = f2bf(e / sm);
}

// Context: per (h,n): C2[i][c=(rr,dd)] = sum_j P[i][j] V[c][j]; scatter to Cb[t][e] bf16.
// grid 24 * (2 x 32) = 1536.
__global__ __launch_bounds__(256) void k_gemm_ctx(
    const unsigned short* __restrict__ P, const unsigned short* __restrict__ V,
    unsigned short* __restrict__ Cb)
{
  __shared__ unsigned short As[128 * LDP], Bs[128 * LDP];
  int bx = blockIdx.x;
  int hn = bx / 64, tt = bx % 64, bm = tt >> 5, bn = tt & 31;
  f32x4 acc[4][4]; ACC_ZERO(acc);
  const unsigned short* Ag = P + (size_t)hn * 65536 + (size_t)bm * 128 * 256;
  const unsigned short* Bg = V + (size_t)hn * 4096 * 256 + (size_t)bn * 128 * 256;
  gemm_core(Ag, 256, Bg, 256, 256, As, Bs, acc);
  EPI_VARS;
  int h = hn >> 1, nn = hn & 1;
#pragma unroll
  for (int mi = 0; mi < 4; ++mi)
#pragma unroll
    for (int ni = 0; ni < 4; ++ni) {
      int c = bn * 128 + wc * 64 + ni * 16 + lr;   // rr*64+dd
      int rr = c >> 6, dd = c & 63;
#pragma unroll
      for (int e = 0; e < 4; ++e) {
        int i = bm * 128 + wr * 64 + mi * 16 + kg * 4 + e;
        int tok = (rr * 256 + i) * 2 + nn;
        Cb[(size_t)tok * 768 + h * 64 + dd] = f2bf(acc[mi][ni][e]);
      }
    }
}

// Output projection: out[t][e] = C @ Wo + bo (fp32 out). grid 256*6 = 1536.
__global__ __launch_bounds__(256) void k_gemm_out(
    const unsigned short* __restrict__ Cb, const unsigned short* __restrict__ woT,
    const float* __restrict__ bo, float* __restrict__ out)
{
  __shared__ unsigned short As[128 * LDP], Bs[128 * LDP];
  int bx = blockIdx.x, bn = bx % 6, bm = bx / 6;
  f32x4 acc[4][4]; ACC_ZERO(acc);
  gemm_core(Cb + (size_t)bm * 128 * 768, 768, woT + (size_t)bn * 128 * 768, 768, 768, As, Bs, acc);
  EPI_VARS;
#pragma unroll
  for (int mi = 0; mi < 4; ++mi)
#pragma unroll
    for (int ni = 0; ni < 4; ++ni) {
      int col = bn * 128 + wc * 64 + ni * 16 + lr;
      float bias = bo[col];
#pragma unroll
      for (int e = 0; e < 4; ++e) {
        int row = bm * 128 + wr * 64 + mi * 16 + kg * 4 + e;
        out[(size_t)row * 768 + col] = acc[mi][ni][e] + bias;
      }
    }
}

// ======================================================================
extern "C" void kernel_launch(void* const* d_in, const int* in_sizes, int n_in,
                              void* d_out, int out_size, void* d_ws, size_t ws_size,
                              hipStream_t stream)
{
  const float* x  = (const float*)d_in[0];
  const float* Wq = (const float*)d_in[1];
  const float* bq = (const float*)d_in[2];
  const float* Wk = (const float*)d_in[3];
  const float* bk = (const float*)d_in[4];
  const float* Wv = (const float*)d_in[5];
  const float* bv = (const float*)d_in[6];
  const float* Wo = (const float*)d_in[7];
  const float* bo = (const float*)d_in[8];
  float* out = (float*)d_out;

  char* ws = (char*)d_ws;
  size_t off = 0;
  auto alloc = [&](size_t bytes) { void* p = ws + off; off += (bytes + 255) & ~(size_t)255; return p; };
  unsigned short* xb   = (unsigned short*)alloc(50331648);   // x bf16 [t][768]
  unsigned short* qkvb = (unsigned short*)alloc(150994944);  // [t][2304] bf16
  unsigned short* Vb   = (unsigned short*)alloc(50331648);   // V [hn][4096][256]
  float*          S    = (float*)alloc(6291456);             // scores [hn][256][256] f32
  unsigned short* P    = (unsigned short*)alloc(3145728);    // probs bf16
  unsigned short* Cb   = (unsigned short*)alloc(50331648);   // context [t][768] bf16
  unsigned short* wT   = (unsigned short*)alloc(3538944);    // [2304][768] bf16
  unsigned short* woT  = (unsigned short*)alloc(1179648);    // [768][768] bf16
  float*          bqkv = (float*)alloc(9216);
  if (off > ws_size) return;  // insufficient workspace: leave output poisoned (diagnosable)

  // Q and K slabs live in d_out (exactly 2 x 50331648 bytes = out bytes); the
  // final GEMM overwrites d_out after scores are consumed.
  unsigned short* Qb = (unsigned short*)d_out;
  unsigned short* Kb = Qb + 25165824;

  k_cvt_x     <<<24576, 256, 0, stream>>>(x, xb);
  k_cvt_w     <<<9225,  256, 0, stream>>>(Wq, Wk, Wv, Wo, bq, bk, bv, wT, woT, bqkv);
  k_gemm_qkv  <<<4608,  256, 0, stream>>>(xb, wT, bqkv, qkvb);
  k_repack_qk <<<24576, 256, 0, stream>>>(qkvb, Qb, 0);
  k_repack_qk <<<24576, 256, 0, stream>>>(qkvb, Kb, 768);
  k_repack_v  <<<6144,  256, 0, stream>>>(qkvb, Vb);
  k_gemm_scores<<<96,   256, 0, stream>>>(Qb, Kb, S);
  k_softmax   <<<6144,  256, 0, stream>>>(S, P);
  k_gemm_ctx  <<<1536,  256, 0, stream>>>(P, Vb, Cb);
  k_gemm_out  <<<1536,  256, 0, stream>>>(Cb, woT, bo, out);
}

// Round 2
// 443.066 us; speedup vs baseline: 1.0243x; 1.0243x over previous
//
#include <hip/hip_runtime.h>
#include <stdint.h>

// ---- types ----
typedef __attribute__((ext_vector_type(8))) short bf16x8;     // 8 x bf16 = 4 VGPR
typedef __attribute__((ext_vector_type(4))) float f32x4;
typedef __attribute__((ext_vector_type(4))) unsigned short us4;
typedef __attribute__((ext_vector_type(8))) unsigned short us8;

// fp32 -> bf16 round-to-nearest-even
static __device__ __forceinline__ unsigned short f2bf(float f) {
  union { float f; unsigned u; } c; c.f = f;
  unsigned r = c.u + 0x7fffu + ((c.u >> 16) & 1u);
  return (unsigned short)(r >> 16);
}

// async global->LDS, 16B per lane. LDS dest must be WAVE-UNIFORM base; HW
// writes lane l at base + l*16 (m97 pattern). Global src is per-lane.
static __device__ __forceinline__ void gl_lds16(const unsigned short* g, unsigned short* l) {
  __builtin_amdgcn_global_load_lds(
      (const __attribute__((address_space(1))) unsigned int*)g,
      (__attribute__((address_space(3))) unsigned int*)l, 16, 0, 0);
}

// Problem constants: x (r=64, i=256, n=2, E=768), h=12, d=64.
// tokens T = 32768 in (r,i,n) order (n fastest); scores K-dim = r*d = 4096; hn = 24.

// ======================================================================
// m97-structure GEMM core: C(128x128) += A(128xK) * B^T (B stored [col][k]).
// 256 threads = 4 waves (2x2), each wave 64x64 = 4x4 frags of 16x16x32.
// BK=64; linear LDS [128][64]; global_load_lds dwordx4 staging; 2 barriers/K-step.
// ======================================================================
__device__ __forceinline__ void gemm_core(
    const unsigned short* __restrict__ Ag, int lda,
    const unsigned short* __restrict__ Bg, int ldb,
    int K, unsigned short* As, unsigned short* Bs, f32x4 acc[4][4])
{
  const int tid  = threadIdx.x;
  const int lane = tid & 63;
  const int wid  = tid >> 6;
  const int wr = wid >> 1, wc = wid & 1;
  const int lr = lane & 15, kg = lane >> 4;

  for (int kt = 0; kt < K; kt += 64) {
#pragma unroll
    for (int c = 0; c < 4; ++c) {          // 1024 16B-chunks/tile, 4 rounds
      int chunk = c * 256 + tid;
      int row = chunk >> 3, ch = chunk & 7;
      unsigned short* lbase = As + ((c * 256 + wid * 64) << 3);  // wave-uniform
      gl_lds16(Ag + row * lda + kt + ch * 8, lbase);
      unsigned short* lbase2 = Bs + ((c * 256 + wid * 64) << 3);
      gl_lds16(Bg + row * ldb + kt + ch * 8, lbase2);
    }
    __syncthreads();                       // vmcnt(0) drain + barrier
#pragma unroll
    for (int ks = 0; ks < 2; ++ks) {
      bf16x8 af[4], bfr[4];
#pragma unroll
      for (int mi = 0; mi < 4; ++mi)
        af[mi] = *reinterpret_cast<const bf16x8*>(As + (wr*64 + mi*16 + lr) * 64 + ks*32 + kg*8);
#pragma unroll
      for (int ni = 0; ni < 4; ++ni)
        bfr[ni] = *reinterpret_cast<const bf16x8*>(Bs + (wc*64 + ni*16 + lr) * 64 + ks*32 + kg*8);
#pragma unroll
      for (int mi = 0; mi < 4; ++mi)
#pragma unroll
        for (int ni = 0; ni < 4; ++ni)
          acc[mi][ni] = __builtin_amdgcn_mfma_f32_16x16x32_bf16(af[mi], bfr[ni], acc[mi][ni], 0, 0, 0);
    }
    __syncthreads();                       // compute done before next overwrite
  }
}

#define ACC_ZERO(acc) do { \
  f32x4 z = {0.f, 0.f, 0.f, 0.f}; \
  for (int a_ = 0; a_ < 4; ++a_) for (int b_ = 0; b_ < 4; ++b_) acc[a_][b_] = z; } while (0)

#define EPI_VARS \
  int tid = threadIdx.x, lane = tid & 63, wid = tid >> 6; \
  int wr = wid >> 1, wc = wid & 1, lr = lane & 15, kg = lane >> 4; (void)wr; (void)wc;

// ======================================================================
// Kernels
// ======================================================================

// x fp32 -> bf16, 4 elems/thread. grid 24576x256 covers 25165824 exactly.
__global__ __launch_bounds__(256) void k_cvt_x(const float* __restrict__ x,
                                               unsigned short* __restrict__ xb) {
  int i = blockIdx.x * 256 + threadIdx.x;
  f32x4 f = reinterpret_cast<const f32x4*>(x)[i];
  us4 o = { f2bf(f[0]), f2bf(f[1]), f2bf(f[2]), f2bf(f[3]) };
  reinterpret_cast<us4*>(xb)[i] = o;
}

// Transposed bf16 weights wT[col][k] (q-part pre-scaled by 1/64), woT[col][k],
// fused bias bqkv (q-part scaled). grid 9225x256 = 2361600 exactly.
__global__ __launch_bounds__(256) void k_cvt_w(
    const float* __restrict__ Wq, const float* __restrict__ Wk, const float* __restrict__ Wv,
    const float* __restrict__ Wo, const float* __restrict__ bq, const float* __restrict__ bk,
    const float* __restrict__ bv, unsigned short* __restrict__ wT,
    unsigned short* __restrict__ woT, float* __restrict__ bqkv)
{
  const float qs = 1.0f / 64.0f;  // d^-0.5 / sqrt(r) = (1/8)/8
  int o = blockIdx.x * 256 + threadIdx.x;
  if (o < 2304 * 768) {
    int col = o / 768, k = o % 768;
    float v;
    if (col < 768)       v = Wq[k * 768 + col] * qs;
    else if (col < 1536) v = Wk[k * 768 + col - 768];
    else                 v = Wv[k * 768 + col - 1536];
    wT[o] = f2bf(v);
  } else if (o < 2304 * 768 + 768 * 768) {
    int o2 = o - 2304 * 768;
    int col = o2 / 768, k = o2 % 768;
    woT[o2] = f2bf(Wo[k * 768 + col]);
  } else {
    int o3 = o - (2304 * 768 + 768 * 768);
    float v = (o3 < 768) ? bq[o3] * qs : (o3 < 1536 ? bk[o3 - 768] : bv[o3 - 1536]);
    bqkv[o3] = v;
  }
}

// QKV projection with FUSED repack: q -> Qb[h][n][i][r*64+d], k -> Kb (same),
// v -> vb[t][768]. grid 4608 (XCD-swizzled, bn-fast within XCD chunk).
__global__ __launch_bounds__(256) void k_gemm_qkv(
    const unsigned short* __restrict__ xb, const unsigned short* __restrict__ wT,
    const float* __restrict__ bqkv, unsigned short* __restrict__ Qb,
    unsigned short* __restrict__ Kb, unsigned short* __restrict__ vb)
{
  __shared__ unsigned short As[128 * 64], Bs[128 * 64];
  int b0 = blockIdx.x;
  int bx = (b0 & 7) * 576 + (b0 >> 3);     // bijective XCD swizzle (4608 % 8 == 0)
  int bn = bx % 18, bm = bx / 18;
  f32x4 acc[4][4]; ACC_ZERO(acc);
  gemm_core(xb + (size_t)bm * 128 * 768, 768, wT + (size_t)bn * 128 * 768, 768, 768, As, Bs, acc);
  EPI_VARS;
#pragma unroll
  for (int mi = 0; mi < 4; ++mi)
#pragma unroll
    for (int ni = 0; ni < 4; ++ni) {
      int col = bn * 128 + wc * 64 + ni * 16 + lr;   // 0..2303
      float bias = bqkv[col];
#pragma unroll
      for (int e = 0; e < 4; ++e) {
        int t = bm * 128 + wr * 64 + mi * 16 + kg * 4 + e;   // token
        unsigned short val = f2bf(acc[mi][ni][e] + bias);
        int nn = t & 1, ii = (t >> 1) & 255, rr = t >> 9;
        if (col < 768) {
          int h = col >> 6, dd = col & 63;
          Qb[(size_t)((h * 2 + nn) * 256 + ii) * 4096 + rr * 64 + dd] = val;
        } else if (col < 1536) {
          int c2 = col - 768, h = c2 >> 6, dd = c2 & 63;
          Kb[(size_t)((h * 2 + nn) * 256 + ii) * 4096 + rr * 64 + dd] = val;
        } else {
          vb[(size_t)t * 768 + (col - 1536)] = val;
        }
      }
    }
}

// Repack v -> V[h][n][rr*64+dd][j=i] (j-contiguous) via LDS 64x64 transpose.
// grid 24*64*4 = 6144 blocks.
#define LDP 80
__global__ __launch_bounds__(256) void k_repack_v(
    const unsigned short* __restrict__ vb, unsigned short* __restrict__ V)
{
  __shared__ unsigned short lds[64 * LDP];
  int bx = blockIdx.x;
  int jt = bx & 3, rr = (bx >> 2) & 63, hn = bx >> 8;
  int h = hn >> 1, nn = hn & 1;
  int t = threadIdx.x;
  int j = t >> 3, ch = t & 7;
#pragma unroll
  for (int p = 0; p < 2; ++p) {
    int jj = p * 32 + j;
    us8 v = *reinterpret_cast<const us8*>(
        vb + (size_t)((rr * 256 + jt * 64 + jj) * 2 + nn) * 768 + h * 64 + ch * 8);
#pragma unroll
    for (int e = 0; e < 8; ++e) lds[(ch * 8 + e) * LDP + jj] = v[e];
  }
  __syncthreads();
  int dd = t >> 2, cj = t & 3;
  size_t ob = ((size_t)(hn * 64 + rr) * 64) * 256;
#pragma unroll
  for (int p = 0; p < 2; ++p) {
    int c2 = cj + p * 4;
    us8 v = *reinterpret_cast<const us8*>(lds + dd * LDP + c2 * 8);
    *reinterpret_cast<us8*>(V + ob + (size_t)dd * 256 + jt * 64 + c2 * 8) = v;
  }
}

// Scores, split-K x4: Spart[s][hn][i][j] = partial over K range [s*1024,(s+1)*1024).
// grid 384 = 4 splits * 24 slabs * (2x2 tiles of 128).
__global__ __launch_bounds__(256) void k_gemm_scores(
    const unsigned short* __restrict__ Qb, const unsigned short* __restrict__ Kb,
    float* __restrict__ Spart)
{
  __shared__ unsigned short As[128 * 64], Bs[128 * 64];
  int bx = blockIdx.x;
  int s = bx / 96, r = bx % 96;
  int hn = r >> 2, tt = r & 3, bm = tt >> 1, bn = tt & 1;
  f32x4 acc[4][4]; ACC_ZERO(acc);
  const unsigned short* Ag = Qb + (size_t)hn * 256 * 4096 + (size_t)bm * 128 * 4096 + s * 1024;
  const unsigned short* Bg = Kb + (size_t)hn * 256 * 4096 + (size_t)bn * 128 * 4096 + s * 1024;
  gemm_core(Ag, 4096, Bg, 4096, 1024, As, Bs, acc);
  EPI_VARS;
  float* Ss = Spart + ((size_t)s * 24 + hn) * 65536;
#pragma unroll
  for (int mi = 0; mi < 4; ++mi)
#pragma unroll
    for (int ni = 0; ni < 4; ++ni)
#pragma unroll
      for (int e = 0; e < 4; ++e) {
        int row = bm * 128 + wr * 64 + mi * 16 + kg * 4 + e;
        int col = bn * 128 + wc * 64 + ni * 16 + lr;
        Ss[(size_t)row * 256 + col] = acc[mi][ni][e];
      }
}

// Row softmax over j=256 with 4-way split-K reduction. grid 6144 (= hn*256+i rows).
__global__ __launch_bounds__(256) void k_softmax(const float* __restrict__ Sp,
                                                 unsigned short* __restrict__ P)
{
  __shared__ float red[8];
  size_t row = blockIdx.x;
  int t = threadIdx.x, wid = t >> 6, lane = t & 63;
  size_t idx = row * 256 + t;
  float v = Sp[idx] + Sp[idx + 1572864] + Sp[idx + 2 * 1572864] + Sp[idx + 3 * 1572864];
  float m = v;
#pragma unroll
  for (int o = 32; o; o >>= 1) m = fmaxf(m, __shfl_xor(m, o));
  if (lane == 0) red[wid] = m;
  __syncthreads();
  m = fmaxf(fmaxf(red[0], red[1]), fmaxf(red[2], red[3]));
  float e = __expf(v - m);
  float sm = e;
#pragma unroll
  for (int o = 32; o; o >>= 1) sm += __shfl_xor(sm, o);
  if (lane == 0) red[4 + wid] = sm;
  __syncthreads();
  sm = red[4] + red[5] + red[6] + red[7];
  P[row * 256 + t] = f2bf(e / sm);
}

// Context: per (h,n): C2[i][c=(rr,dd)] = sum_j P[i][j] V[c][j]; scatter to Cb[t][e].
// grid 24 * (2 x 32) = 1536.
__global__ __launch_bounds__(256) void k_gemm_ctx(
    const unsigned short* __restrict__ P, const unsigned short* __restrict__ V,
    unsigned short* __restrict__ Cb)
{
  __shared__ unsigned short As[128 * 64], Bs[128 * 64];
  int bx = blockIdx.x;
  int hn = bx / 64, tt = bx % 64, bm = tt >> 5, bn = tt & 31;
  f32x4 acc[4][4]; ACC_ZERO(acc);
  const unsigned short* Ag = P + (size_t)hn * 65536 + (size_t)bm * 128 * 256;
  const unsigned short* Bg = V + (size_t)hn * 4096 * 256 + (size_t)bn * 128 * 256;
  gemm_core(Ag, 256, Bg, 256, 256, As, Bs, acc);
  EPI_VARS;
  int nn = hn & 1;
  int h = hn >> 1;
#pragma unroll
  for (int mi = 0; mi < 4; ++mi)
#pragma unroll
    for (int ni = 0; ni < 4; ++ni) {
      int c = bn * 128 + wc * 64 + ni * 16 + lr;   // rr*64+dd
      int rr = c >> 6, dd = c & 63;
#pragma unroll
      for (int e = 0; e < 4; ++e) {
        int i = bm * 128 + wr * 64 + mi * 16 + kg * 4 + e;
        int tok = (rr * 256 + i) * 2 + nn;
        Cb[(size_t)tok * 768 + h * 64 + dd] = f2bf(acc[mi][ni][e]);
      }
    }
}

// Output projection: out[t][e] = C @ Wo + bo (fp32). grid 1536 (XCD-swizzled).
__global__ __launch_bounds__(256) void k_gemm_out(
    const unsigned short* __restrict__ Cb, const unsigned short* __restrict__ woT,
    const float* __restrict__ bo, float* __restrict__ out)
{
  __shared__ unsigned short As[128 * 64], Bs[128 * 64];
  int b0 = blockIdx.x;
  int bx = (b0 & 7) * 192 + (b0 >> 3);     // bijective (1536 % 8 == 0)
  int bn = bx % 6, bm = bx / 6;
  f32x4 acc[4][4]; ACC_ZERO(acc);
  gemm_core(Cb + (size_t)bm * 128 * 768, 768, woT + (size_t)bn * 128 * 768, 768, 768, As, Bs, acc);
  EPI_VARS;
#pragma unroll
  for (int mi = 0; mi < 4; ++mi)
#pragma unroll
    for (int ni = 0; ni < 4; ++ni) {
      int col = bn * 128 + wc * 64 + ni * 16 + lr;
      float bias = bo[col];
#pragma unroll
      for (int e = 0; e < 4; ++e) {
        int row = bm * 128 + wr * 64 + mi * 16 + kg * 4 + e;
        out[(size_t)row * 768 + col] = acc[mi][ni][e] + bias;
      }
    }
}

// ======================================================================
extern "C" void kernel_launch(void* const* d_in, const int* in_sizes, int n_in,
                              void* d_out, int out_size, void* d_ws, size_t ws_size,
                              hipStream_t stream)
{
  const float* x  = (const float*)d_in[0];
  const float* Wq = (const float*)d_in[1];
  const float* bq = (const float*)d_in[2];
  const float* Wk = (const float*)d_in[3];
  const float* bk = (const float*)d_in[4];
  const float* Wv = (const float*)d_in[5];
  const float* bv = (const float*)d_in[6];
  const float* Wo = (const float*)d_in[7];
  const float* bo = (const float*)d_in[8];
  float* out = (float*)d_out;

  char* ws = (char*)d_ws;
  size_t off = 0;
  auto alloc = [&](size_t bytes) { void* p = ws + off; off += (bytes + 255) & ~(size_t)255; return p; };
  unsigned short* xb   = (unsigned short*)alloc(50331648);   // x bf16 [t][768]
  unsigned short* vb   = (unsigned short*)alloc(50331648);   // v bf16 [t][768]
  unsigned short* Vb   = (unsigned short*)alloc(50331648);   // V [hn][4096][256]
  float*          Sp   = (float*)alloc(25165824);            // scores partials [4][hn][256][256]
  unsigned short* P    = (unsigned short*)alloc(3145728);    // probs bf16
  unsigned short* Cb   = (unsigned short*)alloc(50331648);   // context [t][768] bf16
  unsigned short* wT   = (unsigned short*)alloc(3538944);    // [2304][768] bf16
  unsigned short* woT  = (unsigned short*)alloc(1179648);    // [768][768] bf16
  float*          bqkv = (float*)alloc(9216);
  if (off > ws_size) return;

  // Q and K slabs live in d_out (exactly 2 x 50331648 B = out bytes); consumed
  // by scores, then d_out is overwritten by the final GEMM.
  unsigned short* Qb = (unsigned short*)d_out;
  unsigned short* Kb = Qb + 25165824;

  k_cvt_x      <<<24576, 256, 0, stream>>>(x, xb);
  k_cvt_w      <<<9225,  256, 0, stream>>>(Wq, Wk, Wv, Wo, bq, bk, bv, wT, woT, bqkv);
  k_gemm_qkv   <<<4608,  256, 0, stream>>>(xb, wT, bqkv, Qb, Kb, vb);
  k_repack_v   <<<6144,  256, 0, stream>>>(vb, Vb);
  k_gemm_scores<<<384,   256, 0, stream>>>(Qb, Kb, Sp);
  k_softmax    <<<6144,  256, 0, stream>>>(Sp, P);
  k_gemm_ctx   <<<1536,  256, 0, stream>>>(P, Vb, Cb);
  k_gemm_out   <<<1536,  256, 0, stream>>>(Cb, woT, bo, out);
}

// Round 3
// 416.740 us; speedup vs baseline: 1.0890x; 1.0632x over previous
//
#include <hip/hip_runtime.h>
#include <stdint.h>

// ---- types ----
typedef __attribute__((ext_vector_type(8))) short bf16x8;     // 8 x bf16 = 4 VGPR
typedef __attribute__((ext_vector_type(4))) float f32x4;
typedef __attribute__((ext_vector_type(4))) unsigned short us4;
typedef __attribute__((ext_vector_type(8))) unsigned short us8;

// fp32 -> bf16 round-to-nearest-even
static __device__ __forceinline__ unsigned short f2bf(float f) {
  union { float f; unsigned u; } c; c.f = f;
  unsigned r = c.u + 0x7fffu + ((c.u >> 16) & 1u);
  return (unsigned short)(r >> 16);
}

// async global->LDS, 16B per lane. LDS dest must be WAVE-UNIFORM base; HW
// writes lane l at base + l*16 (m97 pattern). Global src is per-lane.
static __device__ __forceinline__ void gl_lds16(const unsigned short* g, unsigned short* l) {
  __builtin_amdgcn_global_load_lds(
      (const __attribute__((address_space(1))) unsigned int*)g,
      (__attribute__((address_space(3))) unsigned int*)l, 16, 0, 0);
}

// Problem constants: x (r=64, i=256, n=2, E=768), h=12, d=64.
// tokens T = 32768 in (r,i,n) order (n fastest); scores K-dim = r*d = 4096; hn = 24.

// ======================================================================
// m97-structure GEMM core + st-style XOR swizzle (rule #21: linear LDS dest,
// inverse-swizzled global SOURCE, same XOR on the ds_read).
// C(128x128) += A(128xK) * B^T (B stored [col][k]).
// 256 threads = 4 waves (2x2), each wave 64x64 = 4x4 frags of 16x16x32.
// BK=64; LDS [128][64] bf16 (128B rows, 8 x 16B units); unit u of row holds
// global column-chunk u ^ (row&7)  -> fragment reads spread over all 32 banks.
// ======================================================================
__device__ __forceinline__ void gemm_core(
    const unsigned short* __restrict__ Ag, int lda,
    const unsigned short* __restrict__ Bg, int ldb,
    int K, unsigned short* As, unsigned short* Bs, f32x4 acc[4][4])
{
  const int tid  = threadIdx.x;
  const int lane = tid & 63;
  const int wid  = tid >> 6;
  const int wr = wid >> 1, wc = wid & 1;
  const int lr = lane & 15, kg = lane >> 4;
  const int l7 = lane & 7;               // == (row & 7) of fragment rows

  for (int kt = 0; kt < K; kt += 64) {
#pragma unroll
    for (int c = 0; c < 4; ++c) {        // 1024 16B-chunks/tile, 4 rounds
      int chunk = c * 256 + tid;
      int row = chunk >> 3, u = chunk & 7;
      int ch = u ^ (row & 7);            // inverse-swizzled source column chunk
      unsigned short* lbase = As + ((c * 256 + wid * 64) << 3);  // wave-uniform
      gl_lds16(Ag + row * lda + kt + ch * 8, lbase);
      unsigned short* lbase2 = Bs + ((c * 256 + wid * 64) << 3);
      gl_lds16(Bg + row * ldb + kt + ch * 8, lbase2);
    }
    __syncthreads();                     // vmcnt(0) drain + barrier
#pragma unroll
    for (int ks = 0; ks < 2; ++ks) {
      bf16x8 af[4], bfr[4];
#pragma unroll
      for (int mi = 0; mi < 4; ++mi) {
        int row = wr*64 + mi*16 + lr;
        int u = (ks*4 + kg) ^ l7;        // swizzled read unit
        af[mi] = *reinterpret_cast<const bf16x8*>(As + row * 64 + u * 8);
      }
#pragma unroll
      for (int ni = 0; ni < 4; ++ni) {
        int row = wc*64 + ni*16 + lr;
        int u = (ks*4 + kg) ^ l7;
        bfr[ni] = *reinterpret_cast<const bf16x8*>(Bs + row * 64 + u * 8);
      }
#pragma unroll
      for (int mi = 0; mi < 4; ++mi)
#pragma unroll
        for (int ni = 0; ni < 4; ++ni)
          acc[mi][ni] = __builtin_amdgcn_mfma_f32_16x16x32_bf16(af[mi], bfr[ni], acc[mi][ni], 0, 0, 0);
    }
    __syncthreads();                     // compute done before next overwrite
  }
}

#define ACC_ZERO(acc) do { \
  f32x4 z = {0.f, 0.f, 0.f, 0.f}; \
  for (int a_ = 0; a_ < 4; ++a_) for (int b_ = 0; b_ < 4; ++b_) acc[a_][b_] = z; } while (0)

#define EPI_VARS \
  int tid = threadIdx.x, lane = tid & 63, wid = tid >> 6; \
  int wr = wid >> 1, wc = wid & 1, lr = lane & 15, kg = lane >> 4; (void)wr; (void)wc;

// ======================================================================
// Kernels
// ======================================================================

// x fp32 -> bf16, 4 elems/thread. grid 24576x256 covers 25165824 exactly.
__global__ __launch_bounds__(256) void k_cvt_x(const float* __restrict__ x,
                                               unsigned short* __restrict__ xb) {
  int i = blockIdx.x * 256 + threadIdx.x;
  f32x4 f = reinterpret_cast<const f32x4*>(x)[i];
  us4 o = { f2bf(f[0]), f2bf(f[1]), f2bf(f[2]), f2bf(f[3]) };
  reinterpret_cast<us4*>(xb)[i] = o;
}

// Transposed bf16 weights wT[col][k] (q-part pre-scaled by 1/64), woT[col][k],
// fused bias bqkv (q-part scaled). grid 9225x256 = 2361600 exactly.
__global__ __launch_bounds__(256) void k_cvt_w(
    const float* __restrict__ Wq, const float* __restrict__ Wk, const float* __restrict__ Wv,
    const float* __restrict__ Wo, const float* __restrict__ bq, const float* __restrict__ bk,
    const float* __restrict__ bv, unsigned short* __restrict__ wT,
    unsigned short* __restrict__ woT, float* __restrict__ bqkv)
{
  const float qs = 1.0f / 64.0f;  // d^-0.5 / sqrt(r) = (1/8)/8
  int o = blockIdx.x * 256 + threadIdx.x;
  if (o < 2304 * 768) {
    int col = o / 768, k = o % 768;
    float v;
    if (col < 768)       v = Wq[k * 768 + col] * qs;
    else if (col < 1536) v = Wk[k * 768 + col - 768];
    else                 v = Wv[k * 768 + col - 1536];
    wT[o] = f2bf(v);
  } else if (o < 2304 * 768 + 768 * 768) {
    int o2 = o - 2304 * 768;
    int col = o2 / 768, k = o2 % 768;
    woT[o2] = f2bf(Wo[k * 768 + col]);
  } else {
    int o3 = o - (2304 * 768 + 768 * 768);
    float v = (o3 < 768) ? bq[o3] * qs : (o3 < 1536 ? bk[o3 - 768] : bv[o3 - 1536]);
    bqkv[o3] = v;
  }
}

// QKV projection with FUSED repack: q -> Qb[h][n][i][r*64+d], k -> Kb (same),
// v -> vb[t][768]. grid 4608 (XCD-swizzled, bn-fast within XCD chunk).
__global__ __launch_bounds__(256) void k_gemm_qkv(
    const unsigned short* __restrict__ xb, const unsigned short* __restrict__ wT,
    const float* __restrict__ bqkv, unsigned short* __restrict__ Qb,
    unsigned short* __restrict__ Kb, unsigned short* __restrict__ vb)
{
  __shared__ unsigned short As[128 * 64], Bs[128 * 64];
  int b0 = blockIdx.x;
  int bx = (b0 & 7) * 576 + (b0 >> 3);     // bijective XCD swizzle (4608 % 8 == 0)
  int bn = bx % 18, bm = bx / 18;
  f32x4 acc[4][4]; ACC_ZERO(acc);
  gemm_core(xb + (size_t)bm * 128 * 768, 768, wT + (size_t)bn * 128 * 768, 768, 768, As, Bs, acc);
  EPI_VARS;
#pragma unroll
  for (int mi = 0; mi < 4; ++mi)
#pragma unroll
    for (int ni = 0; ni < 4; ++ni) {
      int col = bn * 128 + wc * 64 + ni * 16 + lr;   // 0..2303
      float bias = bqkv[col];
#pragma unroll
      for (int e = 0; e < 4; ++e) {
        int t = bm * 128 + wr * 64 + mi * 16 + kg * 4 + e;   // token
        unsigned short val = f2bf(acc[mi][ni][e] + bias);
        int nn = t & 1, ii = (t >> 1) & 255, rr = t >> 9;
        if (col < 768) {
          int h = col >> 6, dd = col & 63;
          Qb[(size_t)((h * 2 + nn) * 256 + ii) * 4096 + rr * 64 + dd] = val;
        } else if (col < 1536) {
          int c2 = col - 768, h = c2 >> 6, dd = c2 & 63;
          Kb[(size_t)((h * 2 + nn) * 256 + ii) * 4096 + rr * 64 + dd] = val;
        } else {
          vb[(size_t)t * 768 + (col - 1536)] = val;
        }
      }
    }
}

// Repack v -> V[h][n][rr*64+dd][j=i] (j-contiguous) via LDS 64x64 transpose.
// grid 24*64*4 = 6144 blocks.
#define LDP 80
__global__ __launch_bounds__(256) void k_repack_v(
    const unsigned short* __restrict__ vb, unsigned short* __restrict__ V)
{
  __shared__ unsigned short lds[64 * LDP];
  int bx = blockIdx.x;
  int jt = bx & 3, rr = (bx >> 2) & 63, hn = bx >> 8;
  int h = hn >> 1, nn = hn & 1;
  int t = threadIdx.x;
  int j = t >> 3, ch = t & 7;
#pragma unroll
  for (int p = 0; p < 2; ++p) {
    int jj = p * 32 + j;
    us8 v = *reinterpret_cast<const us8*>(
        vb + (size_t)((rr * 256 + jt * 64 + jj) * 2 + nn) * 768 + h * 64 + ch * 8);
#pragma unroll
    for (int e = 0; e < 8; ++e) lds[(ch * 8 + e) * LDP + jj] = v[e];
  }
  __syncthreads();
  int dd = t >> 2, cj = t & 3;
  size_t ob = ((size_t)(hn * 64 + rr) * 64) * 256;
#pragma unroll
  for (int p = 0; p < 2; ++p) {
    int c2 = cj + p * 4;
    us8 v = *reinterpret_cast<const us8*>(lds + dd * LDP + c2 * 8);
    *reinterpret_cast<us8*>(V + ob + (size_t)dd * 256 + jt * 64 + c2 * 8) = v;
  }
}

// Scores, split-K x4: Spart[s][hn][i][j] = partial over K range [s*1024,(s+1)*1024).
// grid 384 = 4 splits * 24 slabs * (2x2 tiles of 128).
__global__ __launch_bounds__(256) void k_gemm_scores(
    const unsigned short* __restrict__ Qb, const unsigned short* __restrict__ Kb,
    float* __restrict__ Spart)
{
  __shared__ unsigned short As[128 * 64], Bs[128 * 64];
  int bx = blockIdx.x;
  int s = bx / 96, r = bx % 96;
  int hn = r >> 2, tt = r & 3, bm = tt >> 1, bn = tt & 1;
  f32x4 acc[4][4]; ACC_ZERO(acc);
  const unsigned short* Ag = Qb + (size_t)hn * 256 * 4096 + (size_t)bm * 128 * 4096 + s * 1024;
  const unsigned short* Bg = Kb + (size_t)hn * 256 * 4096 + (size_t)bn * 128 * 4096 + s * 1024;
  gemm_core(Ag, 4096, Bg, 4096, 1024, As, Bs, acc);
  EPI_VARS;
  float* Ss = Spart + ((size_t)s * 24 + hn) * 65536;
#pragma unroll
  for (int mi = 0; mi < 4; ++mi)
#pragma unroll
    for (int ni = 0; ni < 4; ++ni)
#pragma unroll
      for (int e = 0; e < 4; ++e) {
        int row = bm * 128 + wr * 64 + mi * 16 + kg * 4 + e;
        int col = bn * 128 + wc * 64 + ni * 16 + lr;
        Ss[(size_t)row * 256 + col] = acc[mi][ni][e];
      }
}

// Row softmax over j=256 with 4-way split-K reduction. grid 6144 (= hn*256+i rows).
__global__ __launch_bounds__(256) void k_softmax(const float* __restrict__ Sp,
                                                 unsigned short* __restrict__ P)
{
  __shared__ float red[8];
  size_t row = blockIdx.x;
  int t = threadIdx.x, wid = t >> 6, lane = t & 63;
  size_t idx = row * 256 + t;
  float v = Sp[idx] + Sp[idx + 1572864] + Sp[idx + 2 * 1572864] + Sp[idx + 3 * 1572864];
  float m = v;
#pragma unroll
  for (int o = 32; o; o >>= 1) m = fmaxf(m, __shfl_xor(m, o));
  if (lane == 0) red[wid] = m;
  __syncthreads();
  m = fmaxf(fmaxf(red[0], red[1]), fmaxf(red[2], red[3]));
  float e = __expf(v - m);
  float sm = e;
#pragma unroll
  for (int o = 32; o; o >>= 1) sm += __shfl_xor(sm, o);
  if (lane == 0) red[4 + wid] = sm;
  __syncthreads();
  sm = red[4] + red[5] + red[6] + red[7];
  P[row * 256 + t] = f2bf(e / sm);
}

// Context: per (h,n): C2[i][c=(rr,dd)] = sum_j P[i][j] V[c][j]; scatter to Cb[t][e].
// grid 24 * (2 x 32) = 1536.
__global__ __launch_bounds__(256) void k_gemm_ctx(
    const unsigned short* __restrict__ P, const unsigned short* __restrict__ V,
    unsigned short* __restrict__ Cb)
{
  __shared__ unsigned short As[128 * 64], Bs[128 * 64];
  int bx = blockIdx.x;
  int hn = bx / 64, tt = bx % 64, bm = tt >> 5, bn = tt & 31;
  f32x4 acc[4][4]; ACC_ZERO(acc);
  const unsigned short* Ag = P + (size_t)hn * 65536 + (size_t)bm * 128 * 256;
  const unsigned short* Bg = V + (size_t)hn * 4096 * 256 + (size_t)bn * 128 * 256;
  gemm_core(Ag, 256, Bg, 256, 256, As, Bs, acc);
  EPI_VARS;
  int nn = hn & 1;
  int h = hn >> 1;
#pragma unroll
  for (int mi = 0; mi < 4; ++mi)
#pragma unroll
    for (int ni = 0; ni < 4; ++ni) {
      int c = bn * 128 + wc * 64 + ni * 16 + lr;   // rr*64+dd
      int rr = c >> 6, dd = c & 63;
#pragma unroll
      for (int e = 0; e < 4; ++e) {
        int i = bm * 128 + wr * 64 + mi * 16 + kg * 4 + e;
        int tok = (rr * 256 + i) * 2 + nn;
        Cb[(size_t)tok * 768 + h * 64 + dd] = f2bf(acc[mi][ni][e]);
      }
    }
}

// Output projection: out[t][e] = C @ Wo + bo (fp32). grid 1536 (XCD-swizzled).
__global__ __launch_bounds__(256) void k_gemm_out(
    const unsigned short* __restrict__ Cb, const unsigned short* __restrict__ woT,
    const float* __restrict__ bo, float* __restrict__ out)
{
  __shared__ unsigned short As[128 * 64], Bs[128 * 64];
  int b0 = blockIdx.x;
  int bx = (b0 & 7) * 192 + (b0 >> 3);     // bijective (1536 % 8 == 0)
  int bn = bx % 6, bm = bx / 6;
  f32x4 acc[4][4]; ACC_ZERO(acc);
  gemm_core(Cb + (size_t)bm * 128 * 768, 768, woT + (size_t)bn * 128 * 768, 768, 768, As, Bs, acc);
  EPI_VARS;
#pragma unroll
  for (int mi = 0; mi < 4; ++mi)
#pragma unroll
    for (int ni = 0; ni < 4; ++ni) {
      int col = bn * 128 + wc * 64 + ni * 16 + lr;
      float bias = bo[col];
#pragma unroll
      for (int e = 0; e < 4; ++e) {
        int row = bm * 128 + wr * 64 + mi * 16 + kg * 4 + e;
        out[(size_t)row * 768 + col] = acc[mi][ni][e] + bias;
      }
    }
}

// ======================================================================
extern "C" void kernel_launch(void* const* d_in, const int* in_sizes, int n_in,
                              void* d_out, int out_size, void* d_ws, size_t ws_size,
                              hipStream_t stream)
{
  const float* x  = (const float*)d_in[0];
  const float* Wq = (const float*)d_in[1];
  const float* bq = (const float*)d_in[2];
  const float* Wk = (const float*)d_in[3];
  const float* bk = (const float*)d_in[4];
  const float* Wv = (const float*)d_in[5];
  const float* bv = (const float*)d_in[6];
  const float* Wo = (const float*)d_in[7];
  const float* bo = (const float*)d_in[8];
  float* out = (float*)d_out;

  char* ws = (char*)d_ws;
  size_t off = 0;
  auto alloc = [&](size_t bytes) { void* p = ws + off; off += (bytes + 255) & ~(size_t)255; return p; };
  unsigned short* xb   = (unsigned short*)alloc(50331648);   // x bf16 [t][768]
  unsigned short* vb   = (unsigned short*)alloc(50331648);   // v bf16 [t][768]
  unsigned short* Vb   = (unsigned short*)alloc(50331648);   // V [hn][4096][256]
  float*          Sp   = (float*)alloc(25165824);            // scores partials [4][hn][256][256]
  unsigned short* P    = (unsigned short*)alloc(3145728);    // probs bf16
  unsigned short* Cb   = (unsigned short*)alloc(50331648);   // context [t][768] bf16
  unsigned short* wT   = (unsigned short*)alloc(3538944);    // [2304][768] bf16
  unsigned short* woT  = (unsigned short*)alloc(1179648);    // [768][768] bf16
  float*          bqkv = (float*)alloc(9216);
  if (off > ws_size) return;

  // Q and K slabs live in d_out (exactly 2 x 50331648 B = out bytes); consumed
  // by scores, then d_out is overwritten by the final GEMM.
  unsigned short* Qb = (unsigned short*)d_out;
  unsigned short* Kb = Qb + 25165824;

  k_cvt_x      <<<24576, 256, 0, stream>>>(x, xb);
  k_cvt_w      <<<9225,  256, 0, stream>>>(Wq, Wk, Wv, Wo, bq, bk, bv, wT, woT, bqkv);
  k_gemm_qkv   <<<4608,  256, 0, stream>>>(xb, wT, bqkv, Qb, Kb, vb);
  k_repack_v   <<<6144,  256, 0, stream>>>(vb, Vb);
  k_gemm_scores<<<384,   256, 0, stream>>>(Qb, Kb, Sp);
  k_softmax    <<<6144,  256, 0, stream>>>(Sp, P);
  k_gemm_ctx   <<<1536,  256, 0, stream>>>(P, Vb, Cb);
  k_gemm_out   <<<1536,  256, 0, stream>>>(Cb, woT, bo, out);
}

// Round 4
// 413.327 us; speedup vs baseline: 1.0980x; 1.0083x over previous
//
#include <hip/hip_runtime.h>
#include <stdint.h>

// ---- types ----
typedef __attribute__((ext_vector_type(8))) short bf16x8;     // 8 x bf16 = 4 VGPR
typedef __attribute__((ext_vector_type(4))) float f32x4;
typedef __attribute__((ext_vector_type(4))) unsigned short us4;
typedef __attribute__((ext_vector_type(8))) unsigned short us8;

// fp32 -> bf16 round-to-nearest-even
static __device__ __forceinline__ unsigned short f2bf(float f) {
  union { float f; unsigned u; } c; c.f = f;
  unsigned r = c.u + 0x7fffu + ((c.u >> 16) & 1u);
  return (unsigned short)(r >> 16);
}

// async global->LDS, 16B per lane. LDS dest must be WAVE-UNIFORM base; HW
// writes lane l at base + l*16. Global src is per-lane.
static __device__ __forceinline__ void gl_lds16(const unsigned short* g, unsigned short* l) {
  __builtin_amdgcn_global_load_lds(
      (const __attribute__((address_space(1))) unsigned int*)g,
      (__attribute__((address_space(3))) unsigned int*)l, 16, 0, 0);
}

// Problem constants: x (r=64, i=256, n=2, E=768), h=12, d=64.
// tokens T = 32768 in (r,i,n) order (n fastest); scores K-dim = r*d = 4096; hn = 24.

// ======================================================================
// Double-buffered 2-phase GEMM core (T3-minimum recipe):
//   prologue: STAGE(buf0, 0); barrier
//   loop:     STAGE(buf^1, t+1) -> ds_read+MFMA(buf) -> barrier (vmcnt drains
//             the PREFETCH after compute, not before)
// C(128x128) += A(128xK) * B^T (B stored [col][k]). 256 thr = 4 waves (2x2),
// each wave 64x64 = 4x4 frags of 16x16x32. BK=64. LDS: 2 bufs x [128][64] per
// operand (64 KB). XOR swizzle (rule #21): LDS unit u of row holds global
// column-chunk u ^ (row&7); fragment read applies the same XOR.
// ======================================================================
__device__ __forceinline__ void stage_tile(
    const unsigned short* __restrict__ Ag, int lda,
    const unsigned short* __restrict__ Bg, int ldb, int kt,
    unsigned short* As, unsigned short* Bs, int tid, int wid)
{
#pragma unroll
  for (int c = 0; c < 4; ++c) {          // 1024 16B-chunks/tile, 4 rounds
    int chunk = c * 256 + tid;
    int row = chunk >> 3, u = chunk & 7;
    int ch = u ^ (row & 7);              // inverse-swizzled source column chunk
    gl_lds16(Ag + row * lda + kt + ch * 8, As + ((c * 256 + wid * 64) << 3));
    gl_lds16(Bg + row * ldb + kt + ch * 8, Bs + ((c * 256 + wid * 64) << 3));
  }
}

__device__ __forceinline__ void compute_tile(
    const unsigned short* As, const unsigned short* Bs, f32x4 acc[4][4],
    int wr, int wc, int lr, int kg, int l7)
{
#pragma unroll
  for (int ks = 0; ks < 2; ++ks) {
    bf16x8 af[4], bfr[4];
    int u = (ks * 4 + kg) ^ l7;          // swizzled read unit
#pragma unroll
    for (int mi = 0; mi < 4; ++mi)
      af[mi] = *reinterpret_cast<const bf16x8*>(As + (wr*64 + mi*16 + lr) * 64 + u * 8);
#pragma unroll
    for (int ni = 0; ni < 4; ++ni)
      bfr[ni] = *reinterpret_cast<const bf16x8*>(Bs + (wc*64 + ni*16 + lr) * 64 + u * 8);
    __builtin_amdgcn_s_setprio(1);
#pragma unroll
    for (int mi = 0; mi < 4; ++mi)
#pragma unroll
      for (int ni = 0; ni < 4; ++ni)
        acc[mi][ni] = __builtin_amdgcn_mfma_f32_16x16x32_bf16(af[mi], bfr[ni], acc[mi][ni], 0, 0, 0);
    __builtin_amdgcn_s_setprio(0);
  }
}

__device__ __forceinline__ void gemm_core(
    const unsigned short* __restrict__ Ag, int lda,
    const unsigned short* __restrict__ Bg, int ldb,
    int K, unsigned short* As, unsigned short* Bs, f32x4 acc[4][4])
{
  const int tid  = threadIdx.x;
  const int lane = tid & 63;
  const int wid  = tid >> 6;
  const int wr = wid >> 1, wc = wid & 1;
  const int lr = lane & 15, kg = lane >> 4;
  const int l7 = lane & 7;

  const int nt = K >> 6;
  stage_tile(Ag, lda, Bg, ldb, 0, As, Bs, tid, wid);
  __syncthreads();                       // vmcnt(0): tile 0 resident
  int cur = 0;
  for (int t = 0; t < nt - 1; ++t) {
    // issue next tile's loads FIRST -> latency hides under this tile's compute
    stage_tile(Ag, lda, Bg, ldb, (t + 1) << 6,
               As + (cur ^ 1) * 8192, Bs + (cur ^ 1) * 8192, tid, wid);
    compute_tile(As + cur * 8192, Bs + cur * 8192, acc, wr, wc, lr, kg, l7);
    __syncthreads();                     // drains prefetch AFTER compute
    cur ^= 1;
  }
  compute_tile(As + cur * 8192, Bs + cur * 8192, acc, wr, wc, lr, kg, l7);
}

#define ACC_ZERO(acc) do { \
  f32x4 z = {0.f, 0.f, 0.f, 0.f}; \
  for (int a_ = 0; a_ < 4; ++a_) for (int b_ = 0; b_ < 4; ++b_) acc[a_][b_] = z; } while (0)

#define EPI_VARS \
  int tid = threadIdx.x, lane = tid & 63, wid = tid >> 6; \
  int wr = wid >> 1, wc = wid & 1, lr = lane & 15, kg = lane >> 4; (void)wr; (void)wc;

#define GEMM_LDS \
  __shared__ unsigned short As[2 * 128 * 64], Bs[2 * 128 * 64];

// ======================================================================
// Kernels
// ======================================================================

// x fp32 -> bf16, 4 elems/thread. grid 24576x256 covers 25165824 exactly.
__global__ __launch_bounds__(256) void k_cvt_x(const float* __restrict__ x,
                                               unsigned short* __restrict__ xb) {
  int i = blockIdx.x * 256 + threadIdx.x;
  f32x4 f = reinterpret_cast<const f32x4*>(x)[i];
  us4 o = { f2bf(f[0]), f2bf(f[1]), f2bf(f[2]), f2bf(f[3]) };
  reinterpret_cast<us4*>(xb)[i] = o;
}

// Transposed bf16 weights wT[col][k] (q-part pre-scaled by 1/64), woT[col][k],
// fused bias bqkv (q-part scaled). grid 9225x256 = 2361600 exactly.
__global__ __launch_bounds__(256) void k_cvt_w(
    const float* __restrict__ Wq, const float* __restrict__ Wk, const float* __restrict__ Wv,
    const float* __restrict__ Wo, const float* __restrict__ bq, const float* __restrict__ bk,
    const float* __restrict__ bv, unsigned short* __restrict__ wT,
    unsigned short* __restrict__ woT, float* __restrict__ bqkv)
{
  const float qs = 1.0f / 64.0f;  // d^-0.5 / sqrt(r) = (1/8)/8
  int o = blockIdx.x * 256 + threadIdx.x;
  if (o < 2304 * 768) {
    int col = o / 768, k = o % 768;
    float v;
    if (col < 768)       v = Wq[k * 768 + col] * qs;
    else if (col < 1536) v = Wk[k * 768 + col - 768];
    else                 v = Wv[k * 768 + col - 1536];
    wT[o] = f2bf(v);
  } else if (o < 2304 * 768 + 768 * 768) {
    int o2 = o - 2304 * 768;
    int col = o2 / 768, k = o2 % 768;
    woT[o2] = f2bf(Wo[k * 768 + col]);
  } else {
    int o3 = o - (2304 * 768 + 768 * 768);
    float v = (o3 < 768) ? bq[o3] * qs : (o3 < 1536 ? bk[o3 - 768] : bv[o3 - 1536]);
    bqkv[o3] = v;
  }
}

// QKV projection with FUSED repack: q -> Qb[h][n][i][r*64+d], k -> Kb (same),
// v -> vb[t][768]. grid 4608 (XCD-swizzled, bn-fast within XCD chunk).
__global__ __launch_bounds__(256) void k_gemm_qkv(
    const unsigned short* __restrict__ xb, const unsigned short* __restrict__ wT,
    const float* __restrict__ bqkv, unsigned short* __restrict__ Qb,
    unsigned short* __restrict__ Kb, unsigned short* __restrict__ vb)
{
  GEMM_LDS;
  int b0 = blockIdx.x;
  int bx = (b0 & 7) * 576 + (b0 >> 3);     // bijective XCD swizzle (4608 % 8 == 0)
  int bn = bx % 18, bm = bx / 18;
  f32x4 acc[4][4]; ACC_ZERO(acc);
  gemm_core(xb + (size_t)bm * 128 * 768, 768, wT + (size_t)bn * 128 * 768, 768, 768, As, Bs, acc);
  EPI_VARS;
#pragma unroll
  for (int mi = 0; mi < 4; ++mi)
#pragma unroll
    for (int ni = 0; ni < 4; ++ni) {
      int col = bn * 128 + wc * 64 + ni * 16 + lr;   // 0..2303
      float bias = bqkv[col];
#pragma unroll
      for (int e = 0; e < 4; ++e) {
        int t = bm * 128 + wr * 64 + mi * 16 + kg * 4 + e;   // token
        unsigned short val = f2bf(acc[mi][ni][e] + bias);
        int nn = t & 1, ii = (t >> 1) & 255, rr = t >> 9;
        if (col < 768) {
          int h = col >> 6, dd = col & 63;
          Qb[(size_t)((h * 2 + nn) * 256 + ii) * 4096 + rr * 64 + dd] = val;
        } else if (col < 1536) {
          int c2 = col - 768, h = c2 >> 6, dd = c2 & 63;
          Kb[(size_t)((h * 2 + nn) * 256 + ii) * 4096 + rr * 64 + dd] = val;
        } else {
          vb[(size_t)t * 768 + (col - 1536)] = val;
        }
      }
    }
}

// Repack v -> V[h][n][rr*64+dd][j=i] (j-contiguous) via LDS 64x64 transpose.
// grid 24*64*4 = 6144 blocks.
#define LDP 80
__global__ __launch_bounds__(256) void k_repack_v(
    const unsigned short* __restrict__ vb, unsigned short* __restrict__ V)
{
  __shared__ unsigned short lds[64 * LDP];
  int bx = blockIdx.x;
  int jt = bx & 3, rr = (bx >> 2) & 63, hn = bx >> 8;
  int h = hn >> 1, nn = hn & 1;
  int t = threadIdx.x;
  int j = t >> 3, ch = t & 7;
#pragma unroll
  for (int p = 0; p < 2; ++p) {
    int jj = p * 32 + j;
    us8 v = *reinterpret_cast<const us8*>(
        vb + (size_t)((rr * 256 + jt * 64 + jj) * 2 + nn) * 768 + h * 64 + ch * 8);
#pragma unroll
    for (int e = 0; e < 8; ++e) lds[(ch * 8 + e) * LDP + jj] = v[e];
  }
  __syncthreads();
  int dd = t >> 2, cj = t & 3;
  size_t ob = ((size_t)(hn * 64 + rr) * 64) * 256;
#pragma unroll
  for (int p = 0; p < 2; ++p) {
    int c2 = cj + p * 4;
    us8 v = *reinterpret_cast<const us8*>(lds + dd * LDP + c2 * 8);
    *reinterpret_cast<us8*>(V + ob + (size_t)dd * 256 + jt * 64 + c2 * 8) = v;
  }
}

// Scores, split-K x4: Spart[s][hn][i][j] = partial over K range [s*1024,(s+1)*1024).
// grid 384 = 4 splits * 24 slabs * (2x2 tiles of 128).
__global__ __launch_bounds__(256) void k_gemm_scores(
    const unsigned short* __restrict__ Qb, const unsigned short* __restrict__ Kb,
    float* __restrict__ Spart)
{
  GEMM_LDS;
  int bx = blockIdx.x;
  int s = bx / 96, r = bx % 96;
  int hn = r >> 2, tt = r & 3, bm = tt >> 1, bn = tt & 1;
  f32x4 acc[4][4]; ACC_ZERO(acc);
  const unsigned short* Ag = Qb + (size_t)hn * 256 * 4096 + (size_t)bm * 128 * 4096 + s * 1024;
  const unsigned short* Bg = Kb + (size_t)hn * 256 * 4096 + (size_t)bn * 128 * 4096 + s * 1024;
  gemm_core(Ag, 4096, Bg, 4096, 1024, As, Bs, acc);
  EPI_VARS;
  float* Ss = Spart + ((size_t)s * 24 + hn) * 65536;
#pragma unroll
  for (int mi = 0; mi < 4; ++mi)
#pragma unroll
    for (int ni = 0; ni < 4; ++ni)
#pragma unroll
      for (int e = 0; e < 4; ++e) {
        int row = bm * 128 + wr * 64 + mi * 16 + kg * 4 + e;
        int col = bn * 128 + wc * 64 + ni * 16 + lr;
        Ss[(size_t)row * 256 + col] = acc[mi][ni][e];
      }
}

// Row softmax over j=256 with 4-way split-K reduction. grid 6144 (= hn*256+i rows).
__global__ __launch_bounds__(256) void k_softmax(const float* __restrict__ Sp,
                                                 unsigned short* __restrict__ P)
{
  __shared__ float red[8];
  size_t row = blockIdx.x;
  int t = threadIdx.x, wid = t >> 6, lane = t & 63;
  size_t idx = row * 256 + t;
  float v = Sp[idx] + Sp[idx + 1572864] + Sp[idx + 2 * 1572864] + Sp[idx + 3 * 1572864];
  float m = v;
#pragma unroll
  for (int o = 32; o; o >>= 1) m = fmaxf(m, __shfl_xor(m, o));
  if (lane == 0) red[wid] = m;
  __syncthreads();
  m = fmaxf(fmaxf(red[0], red[1]), fmaxf(red[2], red[3]));
  float e = __expf(v - m);
  float sm = e;
#pragma unroll
  for (int o = 32; o; o >>= 1) sm += __shfl_xor(sm, o);
  if (lane == 0) red[4 + wid] = sm;
  __syncthreads();
  sm = red[4] + red[5] + red[6] + red[7];
  P[row * 256 + t] = f2bf(e / sm);
}

// Context: per (h,n): C2[i][c=(rr,dd)] = sum_j P[i][j] V[c][j]; scatter to Cb[t][e].
// grid 24 * (2 x 32) = 1536.
__global__ __launch_bounds__(256) void k_gemm_ctx(
    const unsigned short* __restrict__ P, const unsigned short* __restrict__ V,
    unsigned short* __restrict__ Cb)
{
  GEMM_LDS;
  int bx = blockIdx.x;
  int hn = bx / 64, tt = bx % 64, bm = tt >> 5, bn = tt & 31;
  f32x4 acc[4][4]; ACC_ZERO(acc);
  const unsigned short* Ag = P + (size_t)hn * 65536 + (size_t)bm * 128 * 256;
  const unsigned short* Bg = V + (size_t)hn * 4096 * 256 + (size_t)bn * 128 * 256;
  gemm_core(Ag, 256, Bg, 256, 256, As, Bs, acc);
  EPI_VARS;
  int nn = hn & 1;
  int h = hn >> 1;
#pragma unroll
  for (int mi = 0; mi < 4; ++mi)
#pragma unroll
    for (int ni = 0; ni < 4; ++ni) {
      int c = bn * 128 + wc * 64 + ni * 16 + lr;   // rr*64+dd
      int rr = c >> 6, dd = c & 63;
#pragma unroll
      for (int e = 0; e < 4; ++e) {
        int i = bm * 128 + wr * 64 + mi * 16 + kg * 4 + e;
        int tok = (rr * 256 + i) * 2 + nn;
        Cb[(size_t)tok * 768 + h * 64 + dd] = f2bf(acc[mi][ni][e]);
      }
    }
}

// Output projection: out[t][e] = C @ Wo + bo (fp32). grid 1536 (XCD-swizzled).
__global__ __launch_bounds__(256) void k_gemm_out(
    const unsigned short* __restrict__ Cb, const unsigned short* __restrict__ woT,
    const float* __restrict__ bo, float* __restrict__ out)
{
  GEMM_LDS;
  int b0 = blockIdx.x;
  int bx = (b0 & 7) * 192 + (b0 >> 3);     // bijective (1536 % 8 == 0)
  int bn = bx % 6, bm = bx / 6;
  f32x4 acc[4][4]; ACC_ZERO(acc);
  gemm_core(Cb + (size_t)bm * 128 * 768, 768, woT + (size_t)bn * 128 * 768, 768, 768, As, Bs, acc);
  EPI_VARS;
#pragma unroll
  for (int mi = 0; mi < 4; ++mi)
#pragma unroll
    for (int ni = 0; ni < 4; ++ni) {
      int col = bn * 128 + wc * 64 + ni * 16 + lr;
      float bias = bo[col];
#pragma unroll
      for (int e = 0; e < 4; ++e) {
        int row = bm * 128 + wr * 64 + mi * 16 + kg * 4 + e;
        out[(size_t)row * 768 + col] = acc[mi][ni][e] + bias;
      }
    }
}

// ======================================================================
extern "C" void kernel_launch(void* const* d_in, const int* in_sizes, int n_in,
                              void* d_out, int out_size, void* d_ws, size_t ws_size,
                              hipStream_t stream)
{
  const float* x  = (const float*)d_in[0];
  const float* Wq = (const float*)d_in[1];
  const float* bq = (const float*)d_in[2];
  const float* Wk = (const float*)d_in[3];
  const float* bk = (const float*)d_in[4];
  const float* Wv = (const float*)d_in[5];
  const float* bv = (const float*)d_in[6];
  const float* Wo = (const float*)d_in[7];
  const float* bo = (const float*)d_in[8];
  float* out = (float*)d_out;

  char* ws = (char*)d_ws;
  size_t off = 0;
  auto alloc = [&](size_t bytes) { void* p = ws + off; off += (bytes + 255) & ~(size_t)255; return p; };
  unsigned short* xb   = (unsigned short*)alloc(50331648);   // x bf16 [t][768]
  unsigned short* vb   = (unsigned short*)alloc(50331648);   // v bf16 [t][768]
  unsigned short* Vb   = (unsigned short*)alloc(50331648);   // V [hn][4096][256]
  float*          Sp   = (float*)alloc(25165824);            // scores partials [4][hn][256][256]
  unsigned short* P    = (unsigned short*)alloc(3145728);    // probs bf16
  unsigned short* Cb   = (unsigned short*)alloc(50331648);   // context [t][768] bf16
  unsigned short* wT   = (unsigned short*)alloc(3538944);    // [2304][768] bf16
  unsigned short* woT  = (unsigned short*)alloc(1179648);    // [768][768] bf16
  float*          bqkv = (float*)alloc(9216);
  if (off > ws_size) return;

  // Q and K slabs live in d_out (exactly 2 x 50331648 B = out bytes); consumed
  // by scores, then d_out is overwritten by the final GEMM.
  unsigned short* Qb = (unsigned short*)d_out;
  unsigned short* Kb = Qb + 25165824;

  k_cvt_x      <<<24576, 256, 0, stream>>>(x, xb);
  k_cvt_w      <<<9225,  256, 0, stream>>>(Wq, Wk, Wv, Wo, bq, bk, bv, wT, woT, bqkv);
  k_gemm_qkv   <<<4608,  256, 0, stream>>>(xb, wT, bqkv, Qb, Kb, vb);
  k_repack_v   <<<6144,  256, 0, stream>>>(vb, Vb);
  k_gemm_scores<<<384,   256, 0, stream>>>(Qb, Kb, Sp);
  k_softmax    <<<6144,  256, 0, stream>>>(Sp, P);
  k_gemm_ctx   <<<1536,  256, 0, stream>>>(P, Vb, Cb);
  k_gemm_out   <<<1536,  256, 0, stream>>>(Cb, woT, bo, out);
}

// Round 5
// 409.681 us; speedup vs baseline: 1.1078x; 1.0089x over previous
//
#include <hip/hip_runtime.h>
#include <stdint.h>

// ---- types ----
typedef __attribute__((ext_vector_type(8))) short bf16x8;     // 8 x bf16 = 4 VGPR
typedef __attribute__((ext_vector_type(4))) float f32x4;
typedef __attribute__((ext_vector_type(4))) unsigned short us4;
typedef __attribute__((ext_vector_type(8))) unsigned short us8;

// fp32 -> bf16 round-to-nearest-even
static __device__ __forceinline__ unsigned short f2bf(float f) {
  union { float f; unsigned u; } c; c.f = f;
  unsigned r = c.u + 0x7fffu + ((c.u >> 16) & 1u);
  return (unsigned short)(r >> 16);
}

// Problem constants: x (r=64, i=256, n=2, E=768), h=12, d=64.
// tokens T = 32768 in (r,i,n) order (n fastest); scores K-dim = r*d = 4096; hn = 24.
#define LDP 80   // padded LDS row (160B): conflict-free ds_read_b128 (round-1 measured 0)

// ======================================================================
// Reg-staged GEMM core (round-1 structure, measured 690 TF on qkv here) +
// T14 async-STAGE: issue tile t+1's global loads BEFORE compute(t) so HBM/L2
// latency hides under the 32 MFMAs; ds_write of those regs happens next
// iteration after the buffer-free barrier.
// C(128x128) += A(128xK) * B^T (B stored [col][k]). 256 thr = 4 waves (2x2),
// each wave 64x64 = 4x4 frags of 16x16x32. BK=64. LDS 40KB (2 x 128 x LDP).
// ======================================================================
__device__ __forceinline__ void gemm_core(
    const unsigned short* __restrict__ Ag, int lda,
    const unsigned short* __restrict__ Bg, int ldb,
    int K, unsigned short* As, unsigned short* Bs, f32x4 acc[4][4])
{
  const int tid  = threadIdx.x;
  const int lane = tid & 63;
  const int wid  = tid >> 6;
  const int wr = wid >> 1, wc = wid & 1;
  const int lr = lane & 15, kg = lane >> 4;
  const int srow = tid >> 3, sch = tid & 7;   // staging coords: 32 rows/round x 8 chunks

  us8 av[4], bv[4];
  const int nt = K >> 6;
#pragma unroll
  for (int c = 0; c < 4; ++c) {               // prologue: load tile 0
    int rr = c * 32 + srow;
    av[c] = *reinterpret_cast<const us8*>(Ag + rr * lda + sch * 8);
    bv[c] = *reinterpret_cast<const us8*>(Bg + rr * ldb + sch * 8);
  }
  for (int t = 0; t < nt; ++t) {
    __syncthreads();                          // prior compute done; buffer free
#pragma unroll
    for (int c = 0; c < 4; ++c) {
      int rr = c * 32 + srow;
      *reinterpret_cast<us8*>(As + rr * LDP + sch * 8) = av[c];
      *reinterpret_cast<us8*>(Bs + rr * LDP + sch * 8) = bv[c];
    }
    __syncthreads();                          // tile t resident
    if (t + 1 < nt) {                         // issue t+1 loads EARLY (T14)
      int kt = (t + 1) << 6;
#pragma unroll
      for (int c = 0; c < 4; ++c) {
        int rr = c * 32 + srow;
        av[c] = *reinterpret_cast<const us8*>(Ag + rr * lda + kt + sch * 8);
        bv[c] = *reinterpret_cast<const us8*>(Bg + rr * ldb + kt + sch * 8);
      }
    }
#pragma unroll
    for (int ks = 0; ks < 2; ++ks) {
      bf16x8 af[4], bfr[4];
#pragma unroll
      for (int mi = 0; mi < 4; ++mi)
        af[mi] = *reinterpret_cast<const bf16x8*>(As + (wr*64 + mi*16 + lr) * LDP + ks*32 + kg*8);
#pragma unroll
      for (int ni = 0; ni < 4; ++ni)
        bfr[ni] = *reinterpret_cast<const bf16x8*>(Bs + (wc*64 + ni*16 + lr) * LDP + ks*32 + kg*8);
#pragma unroll
      for (int mi = 0; mi < 4; ++mi)
#pragma unroll
        for (int ni = 0; ni < 4; ++ni)
          acc[mi][ni] = __builtin_amdgcn_mfma_f32_16x16x32_bf16(af[mi], bfr[ni], acc[mi][ni], 0, 0, 0);
    }
  }
}

#define ACC_ZERO(acc) do { \
  f32x4 z = {0.f, 0.f, 0.f, 0.f}; \
  for (int a_ = 0; a_ < 4; ++a_) for (int b_ = 0; b_ < 4; ++b_) acc[a_][b_] = z; } while (0)

#define EPI_VARS \
  int tid = threadIdx.x, lane = tid & 63, wid = tid >> 6; \
  int wr = wid >> 1, wc = wid & 1, lr = lane & 15, kg = lane >> 4; (void)wr; (void)wc;

#define GEMM_LDS \
  __shared__ unsigned short As[128 * LDP], Bs[128 * LDP];

// ======================================================================
// Kernels
// ======================================================================

// x fp32 -> bf16, 4 elems/thread. grid 24576x256 covers 25165824 exactly.
__global__ __launch_bounds__(256) void k_cvt_x(const float* __restrict__ x,
                                               unsigned short* __restrict__ xb) {
  int i = blockIdx.x * 256 + threadIdx.x;
  f32x4 f = reinterpret_cast<const f32x4*>(x)[i];
  us4 o = { f2bf(f[0]), f2bf(f[1]), f2bf(f[2]), f2bf(f[3]) };
  reinterpret_cast<us4*>(xb)[i] = o;
}

// Transposed bf16 weights wT[col][k] (q-part pre-scaled by 1/64), woT[col][k],
// fused bias bqkv (q-part scaled). grid 9225x256 = 2361600 exactly.
__global__ __launch_bounds__(256) void k_cvt_w(
    const float* __restrict__ Wq, const float* __restrict__ Wk, const float* __restrict__ Wv,
    const float* __restrict__ Wo, const float* __restrict__ bq, const float* __restrict__ bk,
    const float* __restrict__ bv, unsigned short* __restrict__ wT,
    unsigned short* __restrict__ woT, float* __restrict__ bqkv)
{
  const float qs = 1.0f / 64.0f;  // d^-0.5 / sqrt(r) = (1/8)/8
  int o = blockIdx.x * 256 + threadIdx.x;
  if (o < 2304 * 768) {
    int col = o / 768, k = o % 768;
    float v;
    if (col < 768)       v = Wq[k * 768 + col] * qs;
    else if (col < 1536) v = Wk[k * 768 + col - 768];
    else                 v = Wv[k * 768 + col - 1536];
    wT[o] = f2bf(v);
  } else if (o < 2304 * 768 + 768 * 768) {
    int o2 = o - 2304 * 768;
    int col = o2 / 768, k = o2 % 768;
    woT[o2] = f2bf(Wo[k * 768 + col]);
  } else {
    int o3 = o - (2304 * 768 + 768 * 768);
    float v = (o3 < 768) ? bq[o3] * qs : (o3 < 1536 ? bk[o3 - 768] : bv[o3 - 1536]);
    bqkv[o3] = v;
  }
}

// QKV projection with FUSED repack: q -> Qb[h][n][i][r*64+d], k -> Kb (same),
// v -> vb[t][768]. grid 4608 (XCD-swizzled, bn-fast within XCD chunk).
__global__ __launch_bounds__(256) void k_gemm_qkv(
    const unsigned short* __restrict__ xb, const unsigned short* __restrict__ wT,
    const float* __restrict__ bqkv, unsigned short* __restrict__ Qb,
    unsigned short* __restrict__ Kb, unsigned short* __restrict__ vb)
{
  GEMM_LDS;
  int b0 = blockIdx.x;
  int bx = (b0 & 7) * 576 + (b0 >> 3);     // bijective XCD swizzle (4608 % 8 == 0)
  int bn = bx % 18, bm = bx / 18;
  f32x4 acc[4][4]; ACC_ZERO(acc);
  gemm_core(xb + (size_t)bm * 128 * 768, 768, wT + (size_t)bn * 128 * 768, 768, 768, As, Bs, acc);
  EPI_VARS;
#pragma unroll
  for (int mi = 0; mi < 4; ++mi)
#pragma unroll
    for (int ni = 0; ni < 4; ++ni) {
      int col = bn * 128 + wc * 64 + ni * 16 + lr;   // 0..2303
      float bias = bqkv[col];
#pragma unroll
      for (int e = 0; e < 4; ++e) {
        int t = bm * 128 + wr * 64 + mi * 16 + kg * 4 + e;   // token
        unsigned short val = f2bf(acc[mi][ni][e] + bias);
        int nn = t & 1, ii = (t >> 1) & 255, rr = t >> 9;
        if (col < 768) {
          int h = col >> 6, dd = col & 63;
          Qb[(size_t)((h * 2 + nn) * 256 + ii) * 4096 + rr * 64 + dd] = val;
        } else if (col < 1536) {
          int c2 = col - 768, h = c2 >> 6, dd = c2 & 63;
          Kb[(size_t)((h * 2 + nn) * 256 + ii) * 4096 + rr * 64 + dd] = val;
        } else {
          vb[(size_t)t * 768 + (col - 1536)] = val;
        }
      }
    }
}

// Repack v -> V[h][n][rr*64+dd][j=i] (j-contiguous) via LDS 64x64 transpose.
// grid 24*64*4 = 6144 blocks.
__global__ __launch_bounds__(256) void k_repack_v(
    const unsigned short* __restrict__ vb, unsigned short* __restrict__ V)
{
  __shared__ unsigned short lds[64 * LDP];
  int bx = blockIdx.x;
  int jt = bx & 3, rr = (bx >> 2) & 63, hn = bx >> 8;
  int h = hn >> 1, nn = hn & 1;
  int t = threadIdx.x;
  int j = t >> 3, ch = t & 7;
#pragma unroll
  for (int p = 0; p < 2; ++p) {
    int jj = p * 32 + j;
    us8 v = *reinterpret_cast<const us8*>(
        vb + (size_t)((rr * 256 + jt * 64 + jj) * 2 + nn) * 768 + h * 64 + ch * 8);
#pragma unroll
    for (int e = 0; e < 8; ++e) lds[(ch * 8 + e) * LDP + jj] = v[e];
  }
  __syncthreads();
  int dd = t >> 2, cj = t & 3;
  size_t ob = ((size_t)(hn * 64 + rr) * 64) * 256;
#pragma unroll
  for (int p = 0; p < 2; ++p) {
    int c2 = cj + p * 4;
    us8 v = *reinterpret_cast<const us8*>(lds + dd * LDP + c2 * 8);
    *reinterpret_cast<us8*>(V + ob + (size_t)dd * 256 + jt * 64 + c2 * 8) = v;
  }
}

// Scores, split-K x4: Spart[s][hn][i][j] = partial over K range [s*1024,(s+1)*1024).
// grid 384 = 4 splits * 24 slabs * (2x2 tiles of 128).
__global__ __launch_bounds__(256) void k_gemm_scores(
    const unsigned short* __restrict__ Qb, const unsigned short* __restrict__ Kb,
    float* __restrict__ Spart)
{
  GEMM_LDS;
  int bx = blockIdx.x;
  int s = bx / 96, r = bx % 96;
  int hn = r >> 2, tt = r & 3, bm = tt >> 1, bn = tt & 1;
  f32x4 acc[4][4]; ACC_ZERO(acc);
  const unsigned short* Ag = Qb + (size_t)hn * 256 * 4096 + (size_t)bm * 128 * 4096 + s * 1024;
  const unsigned short* Bg = Kb + (size_t)hn * 256 * 4096 + (size_t)bn * 128 * 4096 + s * 1024;
  gemm_core(Ag, 4096, Bg, 4096, 1024, As, Bs, acc);
  EPI_VARS;
  float* Ss = Spart + ((size_t)s * 24 + hn) * 65536;
#pragma unroll
  for (int mi = 0; mi < 4; ++mi)
#pragma unroll
    for (int ni = 0; ni < 4; ++ni)
#pragma unroll
      for (int e = 0; e < 4; ++e) {
        int row = bm * 128 + wr * 64 + mi * 16 + kg * 4 + e;
        int col = bn * 128 + wc * 64 + ni * 16 + lr;
        Ss[(size_t)row * 256 + col] = acc[mi][ni][e];
      }
}

// Row softmax over j=256 with 4-way split-K reduction. grid 6144 (= hn*256+i rows).
__global__ __launch_bounds__(256) void k_softmax(const float* __restrict__ Sp,
                                                 unsigned short* __restrict__ P)
{
  __shared__ float red[8];
  size_t row = blockIdx.x;
  int t = threadIdx.x, wid = t >> 6, lane = t & 63;
  size_t idx = row * 256 + t;
  float v = Sp[idx] + Sp[idx + 1572864] + Sp[idx + 2 * 1572864] + Sp[idx + 3 * 1572864];
  float m = v;
#pragma unroll
  for (int o = 32; o; o >>= 1) m = fmaxf(m, __shfl_xor(m, o));
  if (lane == 0) red[wid] = m;
  __syncthreads();
  m = fmaxf(fmaxf(red[0], red[1]), fmaxf(red[2], red[3]));
  float e = __expf(v - m);
  float sm = e;
#pragma unroll
  for (int o = 32; o; o >>= 1) sm += __shfl_xor(sm, o);
  if (lane == 0) red[4 + wid] = sm;
  __syncthreads();
  sm = red[4] + red[5] + red[6] + red[7];
  P[row * 256 + t] = f2bf(e / sm);
}

// Context: per (h,n): C2[i][c=(rr,dd)] = sum_j P[i][j] V[c][j]; scatter to Cb[t][e].
// grid 24 * (2 x 32) = 1536.
__global__ __launch_bounds__(256) void k_gemm_ctx(
    const unsigned short* __restrict__ P, const unsigned short* __restrict__ V,
    unsigned short* __restrict__ Cb)
{
  GEMM_LDS;
  int bx = blockIdx.x;
  int hn = bx / 64, tt = bx % 64, bm = tt >> 5, bn = tt & 31;
  f32x4 acc[4][4]; ACC_ZERO(acc);
  const unsigned short* Ag = P + (size_t)hn * 65536 + (size_t)bm * 128 * 256;
  const unsigned short* Bg = V + (size_t)hn * 4096 * 256 + (size_t)bn * 128 * 256;
  gemm_core(Ag, 256, Bg, 256, 256, As, Bs, acc);
  EPI_VARS;
  int nn = hn & 1;
  int h = hn >> 1;
#pragma unroll
  for (int mi = 0; mi < 4; ++mi)
#pragma unroll
    for (int ni = 0; ni < 4; ++ni) {
      int c = bn * 128 + wc * 64 + ni * 16 + lr;   // rr*64+dd
      int rr = c >> 6, dd = c & 63;
#pragma unroll
      for (int e = 0; e < 4; ++e) {
        int i = bm * 128 + wr * 64 + mi * 16 + kg * 4 + e;
        int tok = (rr * 256 + i) * 2 + nn;
        Cb[(size_t)tok * 768 + h * 64 + dd] = f2bf(acc[mi][ni][e]);
      }
    }
}

// Output projection: out[t][e] = C @ Wo + bo (fp32). grid 1536 (XCD-swizzled).
__global__ __launch_bounds__(256) void k_gemm_out(
    const unsigned short* __restrict__ Cb, const unsigned short* __restrict__ woT,
    const float* __restrict__ bo, float* __restrict__ out)
{
  GEMM_LDS;
  int b0 = blockIdx.x;
  int bx = (b0 & 7) * 192 + (b0 >> 3);     // bijective (1536 % 8 == 0)
  int bn = bx % 6, bm = bx / 6;
  f32x4 acc[4][4]; ACC_ZERO(acc);
  gemm_core(Cb + (size_t)bm * 128 * 768, 768, woT + (size_t)bn * 128 * 768, 768, 768, As, Bs, acc);
  EPI_VARS;
#pragma unroll
  for (int mi = 0; mi < 4; ++mi)
#pragma unroll
    for (int ni = 0; ni < 4; ++ni) {
      int col = bn * 128 + wc * 64 + ni * 16 + lr;
      float bias = bo[col];
#pragma unroll
      for (int e = 0; e < 4; ++e) {
        int row = bm * 128 + wr * 64 + mi * 16 + kg * 4 + e;
        out[(size_t)row * 768 + col] = acc[mi][ni][e] + bias;
      }
    }
}

// ======================================================================
extern "C" void kernel_launch(void* const* d_in, const int* in_sizes, int n_in,
                              void* d_out, int out_size, void* d_ws, size_t ws_size,
                              hipStream_t stream)
{
  const float* x  = (const float*)d_in[0];
  const float* Wq = (const float*)d_in[1];
  const float* bq = (const float*)d_in[2];
  const float* Wk = (const float*)d_in[3];
  const float* bk = (const float*)d_in[4];
  const float* Wv = (const float*)d_in[5];
  const float* bv = (const float*)d_in[6];
  const float* Wo = (const float*)d_in[7];
  const float* bo = (const float*)d_in[8];
  float* out = (float*)d_out;

  char* ws = (char*)d_ws;
  size_t off = 0;
  auto alloc = [&](size_t bytes) { void* p = ws + off; off += (bytes + 255) & ~(size_t)255; return p; };
  unsigned short* xb   = (unsigned short*)alloc(50331648);   // x bf16 [t][768]
  unsigned short* vb   = (unsigned short*)alloc(50331648);   // v bf16 [t][768]
  unsigned short* Vb   = (unsigned short*)alloc(50331648);   // V [hn][4096][256]
  float*          Sp   = (float*)alloc(25165824);            // scores partials [4][hn][256][256]
  unsigned short* P    = (unsigned short*)alloc(3145728);    // probs bf16
  unsigned short* Cb   = (unsigned short*)alloc(50331648);   // context [t][768] bf16
  unsigned short* wT   = (unsigned short*)alloc(3538944);    // [2304][768] bf16
  unsigned short* woT  = (unsigned short*)alloc(1179648);    // [768][768] bf16
  float*          bqkv = (float*)alloc(9216);
  if (off > ws_size) return;

  // Q and K slabs live in d_out (exactly 2 x 50331648 B = out bytes); consumed
  // by scores, then d_out is overwritten by the final GEMM.
  unsigned short* Qb = (unsigned short*)d_out;
  unsigned short* Kb = Qb + 25165824;

  k_cvt_x      <<<24576, 256, 0, stream>>>(x, xb);
  k_cvt_w      <<<9225,  256, 0, stream>>>(Wq, Wk, Wv, Wo, bq, bk, bv, wT, woT, bqkv);
  k_gemm_qkv   <<<4608,  256, 0, stream>>>(xb, wT, bqkv, Qb, Kb, vb);
  k_repack_v   <<<6144,  256, 0, stream>>>(vb, Vb);
  k_gemm_scores<<<384,   256, 0, stream>>>(Qb, Kb, Sp);
  k_softmax    <<<6144,  256, 0, stream>>>(Sp, P);
  k_gemm_ctx   <<<1536,  256, 0, stream>>>(P, Vb, Cb);
  k_gemm_out   <<<1536,  256, 0, stream>>>(Cb, woT, bo, out);
}

// Round 6
// 347.870 us; speedup vs baseline: 1.3047x; 1.1777x over previous
//
#include <hip/hip_runtime.h>
#include <stdint.h>

// ---- types ----
typedef __attribute__((ext_vector_type(8))) short bf16x8;     // 8 x bf16 = 4 VGPR
typedef __attribute__((ext_vector_type(4))) float f32x4;
typedef __attribute__((ext_vector_type(4))) unsigned short us4;
typedef __attribute__((ext_vector_type(8))) unsigned short us8;

// fp32 -> bf16 round-to-nearest-even
static __device__ __forceinline__ unsigned short f2bf(float f) {
  union { float f; unsigned u; } c; c.f = f;
  unsigned r = c.u + 0x7fffu + ((c.u >> 16) & 1u);
  return (unsigned short)(r >> 16);
}

// Problem constants: x (r=64, i=256, n=2, E=768), h=12, d=64.
// tokens T = 32768 in (r,i,n) order (n fastest); scores K-dim = r*d = 4096; hn = 24.
#define LDP 80   // padded LDS row (160B): conflict-free ds_read_b128 (measured 0)

// ======================================================================
// Round-1-verbatim reg-staged GEMM core (measured 690 TF on qkv here).
// C(128x128) += A(128xK) * B^T (B stored [col][k]). 256 thr = 4 waves (2x2),
// each wave 64x64 = 4x4 frags of 16x16x32. BK=64. LDS 40KB (2 x 128 x LDP).
// ======================================================================
__device__ __forceinline__ void gemm_core(
    const unsigned short* __restrict__ Ag, int lda,
    const unsigned short* __restrict__ Bg, int ldb,
    int K, unsigned short* As, unsigned short* Bs, f32x4 acc[4][4])
{
  const int tid  = threadIdx.x;
  const int lane = tid & 63;
  const int wid  = tid >> 6;
  const int wr = wid >> 1, wc = wid & 1;
  const int lr = lane & 15, kg = lane >> 4;

  for (int kt = 0; kt < K; kt += 64) {
    us8 av[4], bv[4];
#pragma unroll
    for (int c = 0; c < 4; ++c) {      // 1024 16B-chunks per tile, 4 per thread
      int idx = c * 256 + tid, row = idx >> 3, ch = idx & 7;
      av[c] = *reinterpret_cast<const us8*>(Ag + row * lda + kt + ch * 8);
      bv[c] = *reinterpret_cast<const us8*>(Bg + row * ldb + kt + ch * 8);
    }
    __syncthreads();                   // prior compute done before overwrite
#pragma unroll
    for (int c = 0; c < 4; ++c) {
      int idx = c * 256 + tid, row = idx >> 3, ch = idx & 7;
      *reinterpret_cast<us8*>(As + row * LDP + ch * 8) = av[c];
      *reinterpret_cast<us8*>(Bs + row * LDP + ch * 8) = bv[c];
    }
    __syncthreads();
#pragma unroll
    for (int ks = 0; ks < 2; ++ks) {   // two k=32 sub-steps per BK=64
      bf16x8 af[4], bfr[4];
#pragma unroll
      for (int mi = 0; mi < 4; ++mi)
        af[mi] = *reinterpret_cast<const bf16x8*>(As + (wr*64 + mi*16 + lr) * LDP + ks*32 + kg*8);
#pragma unroll
      for (int ni = 0; ni < 4; ++ni)
        bfr[ni] = *reinterpret_cast<const bf16x8*>(Bs + (wc*64 + ni*16 + lr) * LDP + ks*32 + kg*8);
#pragma unroll
      for (int mi = 0; mi < 4; ++mi)
#pragma unroll
        for (int ni = 0; ni < 4; ++ni)
          acc[mi][ni] = __builtin_amdgcn_mfma_f32_16x16x32_bf16(af[mi], bfr[ni], acc[mi][ni], 0, 0, 0);
    }
  }
}

#define ACC_ZERO(acc) do { \
  f32x4 z = {0.f, 0.f, 0.f, 0.f}; \
  for (int a_ = 0; a_ < 4; ++a_) for (int b_ = 0; b_ < 4; ++b_) acc[a_][b_] = z; } while (0)

#define EPI_VARS \
  int tid = threadIdx.x, lane = tid & 63, wid = tid >> 6; \
  int wr = wid >> 1, wc = wid & 1, lr = lane & 15, kg = lane >> 4; (void)wr; (void)wc;

#define GEMM_LDS \
  __shared__ unsigned short As[128 * LDP], Bs[128 * LDP];

// ======================================================================
// Kernels
// ======================================================================

// x fp32 -> bf16, 4 elems/thread. grid 24576x256 covers 25165824 exactly.
__global__ __launch_bounds__(256) void k_cvt_x(const float* __restrict__ x,
                                               unsigned short* __restrict__ xb) {
  int i = blockIdx.x * 256 + threadIdx.x;
  f32x4 f = reinterpret_cast<const f32x4*>(x)[i];
  us4 o = { f2bf(f[0]), f2bf(f[1]), f2bf(f[2]), f2bf(f[3]) };
  reinterpret_cast<us4*>(xb)[i] = o;
}

// Transposed bf16 weights wT[col][k] (q-part pre-scaled by 1/64), woT[col][k],
// fused bias bqkv (q-part scaled). grid 9225x256 = 2361600 exactly.
__global__ __launch_bounds__(256) void k_cvt_w(
    const float* __restrict__ Wq, const float* __restrict__ Wk, const float* __restrict__ Wv,
    const float* __restrict__ Wo, const float* __restrict__ bq, const float* __restrict__ bk,
    const float* __restrict__ bv, unsigned short* __restrict__ wT,
    unsigned short* __restrict__ woT, float* __restrict__ bqkv)
{
  const float qs = 1.0f / 64.0f;  // d^-0.5 / sqrt(r) = (1/8)/8
  int o = blockIdx.x * 256 + threadIdx.x;
  if (o < 2304 * 768) {
    int col = o / 768, k = o % 768;
    float v;
    if (col < 768)       v = Wq[k * 768 + col] * qs;
    else if (col < 1536) v = Wk[k * 768 + col - 768];
    else                 v = Wv[k * 768 + col - 1536];
    wT[o] = f2bf(v);
  } else if (o < 2304 * 768 + 768 * 768) {
    int o2 = o - 2304 * 768;
    int col = o2 / 768, k = o2 % 768;
    woT[o2] = f2bf(Wo[k * 768 + col]);
  } else {
    int o3 = o - (2304 * 768 + 768 * 768);
    float v = (o3 < 768) ? bq[o3] * qs : (o3 < 1536 ? bk[o3 - 768] : bv[o3 - 1536]);
    bqkv[o3] = v;
  }
}

// QKV projection, round-1-verbatim: qkvb[t][0..2303] = bf16(x@[Wq|Wk|Wv]+b).
// Clean coalesced epilogue (no scatter). grid 4608, bn-fast.
__global__ __launch_bounds__(256) void k_gemm_qkv(
    const unsigned short* __restrict__ xb, const unsigned short* __restrict__ wT,
    const float* __restrict__ bqkv, unsigned short* __restrict__ qkvb)
{
  GEMM_LDS;
  int bx = blockIdx.x, bn = bx % 18, bm = bx / 18;
  f32x4 acc[4][4]; ACC_ZERO(acc);
  gemm_core(xb + (size_t)bm * 128 * 768, 768, wT + (size_t)bn * 128 * 768, 768, 768, As, Bs, acc);
  EPI_VARS;
#pragma unroll
  for (int mi = 0; mi < 4; ++mi)
#pragma unroll
    for (int ni = 0; ni < 4; ++ni) {
      int col = bn * 128 + wc * 64 + ni * 16 + lr;
      float bias = bqkv[col];
#pragma unroll
      for (int e = 0; e < 4; ++e) {
        int row = bm * 128 + wr * 64 + mi * 16 + kg * 4 + e;   // token
        qkvb[(size_t)row * 2304 + col] = f2bf(acc[mi][ni][e] + bias);
      }
    }
}

// Repack v -> V[h][n][rr*64+dd][j=i] (j-contiguous) via LDS 64x64 transpose.
// Reads qkvb directly. grid 24*64*4 = 6144 blocks.
__global__ __launch_bounds__(256) void k_repack_v(
    const unsigned short* __restrict__ qkvb, unsigned short* __restrict__ V)
{
  __shared__ unsigned short lds[64 * LDP];
  int bx = blockIdx.x;
  int jt = bx & 3, rr = (bx >> 2) & 63, hn = bx >> 8;
  int h = hn >> 1, nn = hn & 1;
  int t = threadIdx.x;
  int j = t >> 3, ch = t & 7;
#pragma unroll
  for (int p = 0; p < 2; ++p) {
    int jj = p * 32 + j;
    us8 v = *reinterpret_cast<const us8*>(
        qkvb + ((size_t)((rr * 256 + jt * 64 + jj) * 2 + nn)) * 2304 + 1536 + h * 64 + ch * 8);
#pragma unroll
    for (int e = 0; e < 8; ++e) lds[(ch * 8 + e) * LDP + jj] = v[e];
  }
  __syncthreads();
  int dd = t >> 2, cj = t & 3;
  size_t ob = ((size_t)(hn * 64 + rr) * 64) * 256;
#pragma unroll
  for (int p = 0; p < 2; ++p) {
    int c2 = cj + p * 4;
    us8 v = *reinterpret_cast<const us8*>(lds + dd * LDP + c2 * 8);
    *reinterpret_cast<us8*>(V + ob + (size_t)dd * 256 + jt * 64 + c2 * 8) = v;
  }
}

// Scores, split-K x4, GATHER-STAGED from qkvb (no Q/K repack buffers).
// One K-tile of 64 = one rr (dd 0..63 contiguous in qkvb). Per 8-lane group
// the staging load is a contiguous 128B segment.
// Spart[s][hn][i][j] = partial over rr in [s*16,(s+1)*16). grid 384.
__global__ __launch_bounds__(256) void k_gemm_scores(
    const unsigned short* __restrict__ qkvb, float* __restrict__ Spart)
{
  GEMM_LDS;
  int bx = blockIdx.x;
  int s = bx / 96, rblk = bx % 96;
  int hn = rblk >> 2, tt = rblk & 3, bm = tt >> 1, bn = tt & 1;
  int h = hn >> 1, nn = hn & 1;
  const int hq = h * 64;
  f32x4 acc[4][4]; ACC_ZERO(acc);

  const int tid = threadIdx.x, lane = tid & 63, wid = tid >> 6;
  const int wr = wid >> 1, wc = wid & 1, lr = lane & 15, kg = lane >> 4;
  const int srow = tid >> 3, sch = tid & 7;

  for (int t = 0; t < 16; ++t) {
    int rr = s * 16 + t;
    us8 av[4], bv[4];
#pragma unroll
    for (int c = 0; c < 4; ++c) {
      int row = c * 32 + srow;
      size_t ab = ((size_t)((rr * 256 + bm * 128 + row) * 2 + nn)) * 2304 + hq + sch * 8;
      size_t bb = ((size_t)((rr * 256 + bn * 128 + row) * 2 + nn)) * 2304 + 768 + hq + sch * 8;
      av[c] = *reinterpret_cast<const us8*>(qkvb + ab);
      bv[c] = *reinterpret_cast<const us8*>(qkvb + bb);
    }
    __syncthreads();
#pragma unroll
    for (int c = 0; c < 4; ++c) {
      int row = c * 32 + srow;
      *reinterpret_cast<us8*>(As + row * LDP + sch * 8) = av[c];
      *reinterpret_cast<us8*>(Bs + row * LDP + sch * 8) = bv[c];
    }
    __syncthreads();
#pragma unroll
    for (int ks = 0; ks < 2; ++ks) {
      bf16x8 af[4], bfr[4];
#pragma unroll
      for (int mi = 0; mi < 4; ++mi)
        af[mi] = *reinterpret_cast<const bf16x8*>(As + (wr*64 + mi*16 + lr) * LDP + ks*32 + kg*8);
#pragma unroll
      for (int ni = 0; ni < 4; ++ni)
        bfr[ni] = *reinterpret_cast<const bf16x8*>(Bs + (wc*64 + ni*16 + lr) * LDP + ks*32 + kg*8);
#pragma unroll
      for (int mi = 0; mi < 4; ++mi)
#pragma unroll
        for (int ni = 0; ni < 4; ++ni)
          acc[mi][ni] = __builtin_amdgcn_mfma_f32_16x16x32_bf16(af[mi], bfr[ni], acc[mi][ni], 0, 0, 0);
    }
  }

  float* Ss = Spart + ((size_t)s * 24 + hn) * 65536;
#pragma unroll
  for (int mi = 0; mi < 4; ++mi)
#pragma unroll
    for (int ni = 0; ni < 4; ++ni)
#pragma unroll
      for (int e = 0; e < 4; ++e) {
        int row = bm * 128 + wr * 64 + mi * 16 + kg * 4 + e;
        int col = bn * 128 + wc * 64 + ni * 16 + lr;
        Ss[(size_t)row * 256 + col] = acc[mi][ni][e];
      }
}

// Row softmax over j=256 with 4-way split-K reduction. grid 6144 (= hn*256+i rows).
__global__ __launch_bounds__(256) void k_softmax(const float* __restrict__ Sp,
                                                 unsigned short* __restrict__ P)
{
  __shared__ float red[8];
  size_t row = blockIdx.x;
  int t = threadIdx.x, wid = t >> 6, lane = t & 63;
  size_t idx = row * 256 + t;
  float v = Sp[idx] + Sp[idx + 1572864] + Sp[idx + 2 * 1572864] + Sp[idx + 3 * 1572864];
  float m = v;
#pragma unroll
  for (int o = 32; o; o >>= 1) m = fmaxf(m, __shfl_xor(m, o));
  if (lane == 0) red[wid] = m;
  __syncthreads();
  m = fmaxf(fmaxf(red[0], red[1]), fmaxf(red[2], red[3]));
  float e = __expf(v - m);
  float sm = e;
#pragma unroll
  for (int o = 32; o; o >>= 1) sm += __shfl_xor(sm, o);
  if (lane == 0) red[4 + wid] = sm;
  __syncthreads();
  sm = red[4] + red[5] + red[6] + red[7];
  P[row * 256 + t] = f2bf(e / sm);
}

// Context: per (h,n): C2[i][c=(rr,dd)] = sum_j P[i][j] V[c][j]; scatter to Cb[t][e].
// grid 24 * (2 x 32) = 1536.
__global__ __launch_bounds__(256) void k_gemm_ctx(
    const unsigned short* __restrict__ P, const unsigned short* __restrict__ V,
    unsigned short* __restrict__ Cb)
{
  GEMM_LDS;
  int bx = blockIdx.x;
  int hn = bx / 64, tt = bx % 64, bm = tt >> 5, bn = tt & 31;
  f32x4 acc[4][4]; ACC_ZERO(acc);
  const unsigned short* Ag = P + (size_t)hn * 65536 + (size_t)bm * 128 * 256;
  const unsigned short* Bg = V + (size_t)hn * 4096 * 256 + (size_t)bn * 128 * 256;
  gemm_core(Ag, 256, Bg, 256, 256, As, Bs, acc);
  EPI_VARS;
  int nn = hn & 1;
  int h = hn >> 1;
#pragma unroll
  for (int mi = 0; mi < 4; ++mi)
#pragma unroll
    for (int ni = 0; ni < 4; ++ni) {
      int c = bn * 128 + wc * 64 + ni * 16 + lr;   // rr*64+dd
      int rr = c >> 6, dd = c & 63;
#pragma unroll
      for (int e = 0; e < 4; ++e) {
        int i = bm * 128 + wr * 64 + mi * 16 + kg * 4 + e;
        int tok = (rr * 256 + i) * 2 + nn;
        Cb[(size_t)tok * 768 + h * 64 + dd] = f2bf(acc[mi][ni][e]);
      }
    }
}

// Output projection: out[t][e] = C @ Wo + bo (fp32). grid 1536 (XCD-swizzled).
__global__ __launch_bounds__(256) void k_gemm_out(
    const unsigned short* __restrict__ Cb, const unsigned short* __restrict__ woT,
    const float* __restrict__ bo, float* __restrict__ out)
{
  GEMM_LDS;
  int b0 = blockIdx.x;
  int bx = (b0 & 7) * 192 + (b0 >> 3);     // bijective (1536 % 8 == 0)
  int bn = bx % 6, bm = bx / 6;
  f32x4 acc[4][4]; ACC_ZERO(acc);
  gemm_core(Cb + (size_t)bm * 128 * 768, 768, woT + (size_t)bn * 128 * 768, 768, 768, As, Bs, acc);
  EPI_VARS;
#pragma unroll
  for (int mi = 0; mi < 4; ++mi)
#pragma unroll
    for (int ni = 0; ni < 4; ++ni) {
      int col = bn * 128 + wc * 64 + ni * 16 + lr;
      float bias = bo[col];
#pragma unroll
      for (int e = 0; e < 4; ++e) {
        int row = bm * 128 + wr * 64 + mi * 16 + kg * 4 + e;
        out[(size_t)row * 768 + col] = acc[mi][ni][e] + bias;
      }
    }
}

// ======================================================================
extern "C" void kernel_launch(void* const* d_in, const int* in_sizes, int n_in,
                              void* d_out, int out_size, void* d_ws, size_t ws_size,
                              hipStream_t stream)
{
  const float* x  = (const float*)d_in[0];
  const float* Wq = (const float*)d_in[1];
  const float* bq = (const float*)d_in[2];
  const float* Wk = (const float*)d_in[3];
  const float* bk = (const float*)d_in[4];
  const float* Wv = (const float*)d_in[5];
  const float* bv = (const float*)d_in[6];
  const float* Wo = (const float*)d_in[7];
  const float* bo = (const float*)d_in[8];
  float* out = (float*)d_out;

  char* ws = (char*)d_ws;
  size_t off = 0;
  auto alloc = [&](size_t bytes) { void* p = ws + off; off += (bytes + 255) & ~(size_t)255; return p; };
  unsigned short* xb   = (unsigned short*)alloc(50331648);   // x bf16 [t][768]
  unsigned short* qkvb = (unsigned short*)alloc(150994944);  // [t][2304] bf16
  unsigned short* Vb   = (unsigned short*)alloc(50331648);   // V [hn][4096][256]
  unsigned short* Cb   = (unsigned short*)alloc(50331648);   // context [t][768] bf16
  unsigned short* wT   = (unsigned short*)alloc(3538944);    // [2304][768] bf16
  unsigned short* woT  = (unsigned short*)alloc(1179648);    // [768][768] bf16
  float*          bqkv = (float*)alloc(9216);
  if (off > ws_size) return;

  // Scores partials + probs live in d_out (28.3MB of 100.6MB); both are fully
  // consumed by k_gemm_ctx before k_gemm_out overwrites d_out with the result.
  float*          Sp = (float*)d_out;                                   // [4][hn][256][256] f32
  unsigned short* P  = (unsigned short*)((char*)d_out + 25165824);      // [hn][256][256] bf16

  k_cvt_x      <<<24576, 256, 0, stream>>>(x, xb);
  k_cvt_w      <<<9225,  256, 0, stream>>>(Wq, Wk, Wv, Wo, bq, bk, bv, wT, woT, bqkv);
  k_gemm_qkv   <<<4608,  256, 0, stream>>>(xb, wT, bqkv, qkvb);
  k_repack_v   <<<6144,  256, 0, stream>>>(qkvb, Vb);
  k_gemm_scores<<<384,   256, 0, stream>>>(qkvb, Sp);
  k_softmax    <<<6144,  256, 0, stream>>>(Sp, P);
  k_gemm_ctx   <<<1536,  256, 0, stream>>>(P, Vb, Cb);
  k_gemm_out   <<<1536,  256, 0, stream>>>(Cb, woT, bo, out);
}